// Round 4
// baseline (715.311 us; speedup 1.0000x reference)
//
#include <hip/hip_runtime.h>
#include <hip/hip_bf16.h>

#define NN 50000
#define NE 800000
#define HH 128
#define SCAN_NB 196  // ceil(50000/256)

typedef short s16x8 __attribute__((ext_vector_type(8)));
typedef float f32x4 __attribute__((ext_vector_type(4)));

__device__ __forceinline__ float bf2f(unsigned short u) {
    unsigned int v = ((unsigned int)u) << 16;
    float f;
    __builtin_memcpy(&f, &v, 4);
    return f;
}
__device__ __forceinline__ unsigned short f2bf(float f) {
    unsigned int x;
    __builtin_memcpy(&x, &f, 4);
    unsigned int r = (x + 0x7fffu + ((x >> 16) & 1u)) >> 16;
    return (unsigned short)r;
}
__device__ __forceinline__ float silu(float v) { return v / (1.f + __expf(-v)); }

// ---- h f32 -> bf16 pre-pass ----
__global__ void h2bf_k(const float* __restrict__ h, unsigned short* __restrict__ hbf) {
    int i = blockIdx.x * 256 + threadIdx.x;  // one per 8 elems
    if (i >= NN * HH / 8) return;
    const f32x4* p = (const f32x4*)&h[i * 8];
    f32x4 a = p[0], b = p[1];
    s16x8 s;
#pragma unroll
    for (int j = 0; j < 4; j++) {
        s[j] = (short)f2bf(a[j]);
        s[j + 4] = (short)f2bf(b[j]);
    }
    *(s16x8*)&hbf[i * 8] = s;
}

// ---- weight transpose+cast: W[k][128] f32 -> WT[n][K] bf16 ----
__global__ void transpose_w(const float* __restrict__ W,
                            unsigned short* __restrict__ WT, int K) {
    int idx = blockIdx.x * 256 + threadIdx.x;
    if (idx >= 128 * K) return;
    int n = idx / K, k = idx - n * K;
    WT[idx] = f2bf(W[k * 128 + n]);
}

// ---- CSR build ----
__global__ void k_count(const int* __restrict__ eidx, int* __restrict__ counts) {
    int e = blockIdx.x * 256 + threadIdx.x;
    if (e >= NE) return;
    int r = eidx[e];
    r = r < 0 ? 0 : (r >= NN ? NN - 1 : r);
    atomicAdd(&counts[r], 1);
}
__global__ void k_partial(const int* __restrict__ counts, int* __restrict__ partials) {
    __shared__ int sm[256];
    int idx = blockIdx.x * 256 + threadIdx.x;
    sm[threadIdx.x] = idx < NN ? counts[idx] : 0;
    __syncthreads();
    for (int s = 128; s > 0; s >>= 1) {
        if (threadIdx.x < s) sm[threadIdx.x] += sm[threadIdx.x + s];
        __syncthreads();
    }
    if (threadIdx.x == 0) partials[blockIdx.x] = sm[0];
}
__global__ void k_scanp(const int* __restrict__ partials, int* __restrict__ scanp) {
    __shared__ int sm[256];
    int t = threadIdx.x;
    int v = t < SCAN_NB ? partials[t] : 0;
    sm[t] = v;
    __syncthreads();
    for (int d = 1; d < 256; d <<= 1) {
        int add = t >= d ? sm[t - d] : 0;
        __syncthreads();
        sm[t] += add;
        __syncthreads();
    }
    scanp[t] = sm[t] - v;  // exclusive
}
__global__ void k_offsets(const int* __restrict__ counts, const int* __restrict__ scanp,
                          int* __restrict__ offsets) {
    __shared__ int sm[256];
    int t = threadIdx.x, idx = blockIdx.x * 256 + t;
    int v = idx < NN ? counts[idx] : 0;
    sm[t] = v;
    __syncthreads();
    for (int d = 1; d < 256; d <<= 1) {
        int add = t >= d ? sm[t - d] : 0;
        __syncthreads();
        sm[t] += add;
        __syncthreads();
    }
    if (idx < NN) offsets[idx] = sm[t] - v + scanp[blockIdx.x];
}
// sort edges into CSR slot order: rs/cs indexed by slot
__global__ void k_fill(const int* __restrict__ eidx, const int* __restrict__ offsets,
                       int* __restrict__ cursor, int* __restrict__ rs,
                       int* __restrict__ cs) {
    int e = blockIdx.x * 256 + threadIdx.x;
    if (e >= NE) return;
    int r = eidx[e];
    int c = eidx[NE + e];
    r = r < 0 ? 0 : (r >= NN ? NN - 1 : r);
    c = c < 0 ? 0 : (c >= NN ? NN - 1 : c);
    int slot = offsets[r] + atomicAdd(&cursor[r], 1);
    rs[slot] = r;
    cs[slot] = c;
}

// ---- edge kernel: 64 edge-slots per block, 4 waves ----
// BIG: slots are CSR-sorted via rs/cs; m_ij bf16 -> mixbuf (sequential).
// !BIG: natural edge order from eidx; atomicAdd into m_i.
template <bool BIG>
__global__ __launch_bounds__(256, 3) void edge_kernel(
    const unsigned short* __restrict__ hbf, const float* __restrict__ x,
    const int* __restrict__ eidx, const int* __restrict__ rs,
    const int* __restrict__ cs,
    const unsigned short* __restrict__ W1T, const float* __restrict__ b1,
    const float* __restrict__ W1full,  // [257][128] f32, row 256 = radial row
    const unsigned short* __restrict__ W2T, const float* __restrict__ b2,
    const unsigned short* __restrict__ Wc1T, const float* __restrict__ bc1,
    const float* __restrict__ wc2,
    float* __restrict__ m_i, unsigned short* __restrict__ mixbuf,
    float* __restrict__ x_acc) {
    __shared__ unsigned short Alds[64 * 264];  // [64 slots][256+8] bf16 (A for e1)
    __shared__ unsigned short mid1[64 * 136];  // [64][128+8]
    unsigned short* mid2 = Alds;               // alias: A dead after e1 k-loop
    __shared__ float rad[64], ndx[64], ndy[64], ndz[64], fsum[64];
    __shared__ int rowA[64], colA[64];

    const int tid = threadIdx.x;
    const int e0 = blockIdx.x * 64;

    if (tid < 64) {
        int r, c;
        if (BIG) {
            r = rs[e0 + tid];
            c = cs[e0 + tid];
        } else {
            r = eidx[e0 + tid];
            c = eidx[NE + e0 + tid];
            r = r < 0 ? 0 : (r >= NN ? NN - 1 : r);
            c = c < 0 ? 0 : (c >= NN ? NN - 1 : c);
        }
        rowA[tid] = r; colA[tid] = c;
        float dx = x[r * 3 + 0] - x[c * 3 + 0];
        float dy = x[r * 3 + 1] - x[c * 3 + 1];
        float dz = x[r * 3 + 2] - x[c * 3 + 2];
        float d2 = dx * dx + dy * dy + dz * dz;
        float dist = sqrtf(d2);
        float inv = 1.f / (dist + 1e-8f);
        rad[tid] = d2;
        ndx[tid] = dx * inv; ndy[tid] = dy * inv; ndz[tid] = dz * inv;
        fsum[tid] = 0.f;
    }
    __syncthreads();

    // stage A = [hbf[row] | hbf[col]] : pure 16B copies, no conversion
#pragma unroll
    for (int i = 0; i < 8; i++) {
        int idx = tid + i * 256;
        int hr = idx >> 4, ch = idx & 15;
        int e = hr >> 1, half = hr & 1;
        int node = half ? colA[e] : rowA[e];
        *(s16x8*)&Alds[e * 264 + half * 128 + ch * 8] =
            *(const s16x8*)&hbf[node * 128 + ch * 8];
    }
    __syncthreads();

    const int lane = tid & 63;
    const int w = tid >> 6;
    const int ln15 = lane & 15;
    const int q8 = (lane >> 4) * 8, q4 = (lane >> 4) * 4;
    const int nbase = w * 32;

    f32x4 acc[4][2];

    // ---- layer e1: [64x256]@W1 + bias + radial*W1[256], silu -> mid1
#pragma unroll
    for (int et = 0; et < 4; et++)
#pragma unroll
        for (int nt = 0; nt < 2; nt++) acc[et][nt] = (f32x4){0.f, 0.f, 0.f, 0.f};
#pragma unroll
    for (int kk = 0; kk < 8; kk++) {
        int k0 = kk * 32 + q8;
        s16x8 a[4], b[2];
#pragma unroll
        for (int et = 0; et < 4; et++)
            a[et] = *(const s16x8*)&Alds[(et * 16 + ln15) * 264 + k0];
#pragma unroll
        for (int nt = 0; nt < 2; nt++)
            b[nt] = *(const s16x8*)&W1T[(nbase + nt * 16 + ln15) * 256 + k0];
#pragma unroll
        for (int et = 0; et < 4; et++)
#pragma unroll
            for (int nt = 0; nt < 2; nt++)
                acc[et][nt] = __builtin_amdgcn_mfma_f32_16x16x32_bf16(
                    a[et], b[nt], acc[et][nt], 0, 0, 0);
    }
#pragma unroll
    for (int nt = 0; nt < 2; nt++) {
        int col = nbase + nt * 16 + ln15;
        float bias = b1[col];
        float wlast = W1full[256 * 128 + col];
#pragma unroll
        for (int et = 0; et < 4; et++)
#pragma unroll
            for (int r = 0; r < 4; r++) {
                int row = et * 16 + q4 + r;
                float v = acc[et][nt][r] + bias + rad[row] * wlast;
                mid1[row * 136 + col] = f2bf(silu(v));
            }
    }
    __syncthreads();

    // ---- layer e2: silu([64x128]@W2 + b2) = m_ij -> mid2 (+ atomics if !BIG)
#pragma unroll
    for (int et = 0; et < 4; et++)
#pragma unroll
        for (int nt = 0; nt < 2; nt++) acc[et][nt] = (f32x4){0.f, 0.f, 0.f, 0.f};
#pragma unroll
    for (int kk = 0; kk < 4; kk++) {
        int k0 = kk * 32 + q8;
        s16x8 a[4], b[2];
#pragma unroll
        for (int et = 0; et < 4; et++)
            a[et] = *(const s16x8*)&mid1[(et * 16 + ln15) * 136 + k0];
#pragma unroll
        for (int nt = 0; nt < 2; nt++)
            b[nt] = *(const s16x8*)&W2T[(nbase + nt * 16 + ln15) * 128 + k0];
#pragma unroll
        for (int et = 0; et < 4; et++)
#pragma unroll
            for (int nt = 0; nt < 2; nt++)
                acc[et][nt] = __builtin_amdgcn_mfma_f32_16x16x32_bf16(
                    a[et], b[nt], acc[et][nt], 0, 0, 0);
    }
#pragma unroll
    for (int nt = 0; nt < 2; nt++) {
        int col = nbase + nt * 16 + ln15;
        float bias = b2[col];
#pragma unroll
        for (int et = 0; et < 4; et++)
#pragma unroll
            for (int r = 0; r < 4; r++) {
                int row = et * 16 + q4 + r;
                float v = silu(acc[et][nt][r] + bias);
                if (!BIG) atomicAdd(&m_i[rowA[row] * 128 + col], v);
                mid2[row * 136 + col] = f2bf(v);
            }
    }
    __syncthreads();

    // ---- coord layer: c1 = silu(m_ij @ Wc1 + bc1); fs = tanh(c1.wc2)*0.1
#pragma unroll
    for (int et = 0; et < 4; et++)
#pragma unroll
        for (int nt = 0; nt < 2; nt++) acc[et][nt] = (f32x4){0.f, 0.f, 0.f, 0.f};
#pragma unroll
    for (int kk = 0; kk < 4; kk++) {
        int k0 = kk * 32 + q8;
        s16x8 a[4], b[2];
#pragma unroll
        for (int et = 0; et < 4; et++)
            a[et] = *(const s16x8*)&mid2[(et * 16 + ln15) * 136 + k0];
#pragma unroll
        for (int nt = 0; nt < 2; nt++)
            b[nt] = *(const s16x8*)&Wc1T[(nbase + nt * 16 + ln15) * 128 + k0];
#pragma unroll
        for (int et = 0; et < 4; et++)
#pragma unroll
            for (int nt = 0; nt < 2; nt++)
                acc[et][nt] = __builtin_amdgcn_mfma_f32_16x16x32_bf16(
                    a[et], b[nt], acc[et][nt], 0, 0, 0);
    }

    if (BIG) {  // coalesced, CSR-ordered m_ij export
#pragma unroll
        for (int j = 0; j < 4; j++) {
            int c = tid + j * 256;
            int row = c >> 4, ch = c & 15;
            *(s16x8*)&mixbuf[(size_t)(e0 + row) * 128 + ch * 8] =
                *(s16x8*)&mid2[row * 136 + ch * 8];
        }
    }

    {
        float part[4][4];
#pragma unroll
        for (int et = 0; et < 4; et++)
#pragma unroll
            for (int r = 0; r < 4; r++) part[et][r] = 0.f;
#pragma unroll
        for (int nt = 0; nt < 2; nt++) {
            int col = nbase + nt * 16 + ln15;
            float bias = bc1[col];
            float w2 = wc2[col];
#pragma unroll
            for (int et = 0; et < 4; et++)
#pragma unroll
                for (int r = 0; r < 4; r++)
                    part[et][r] += silu(acc[et][nt][r] + bias) * w2;
        }
#pragma unroll
        for (int et = 0; et < 4; et++)
#pragma unroll
            for (int r = 0; r < 4; r++) {
                float p = part[et][r];
                p += __shfl_xor(p, 8, 16);
                p += __shfl_xor(p, 4, 16);
                p += __shfl_xor(p, 2, 16);
                p += __shfl_xor(p, 1, 16);
                if (ln15 == 0) atomicAdd(&fsum[et * 16 + q4 + r], p);
            }
    }
    __syncthreads();
    if (tid < 64) {
        float fs = tanhf(fsum[tid]) * 0.1f;
        int rn = rowA[tid];
        atomicAdd(&x_acc[rn * 3 + 0], ndx[tid] * fs);
        atomicAdd(&x_acc[rn * 3 + 1], ndy[tid] * fs);
        atomicAdd(&x_acc[rn * 3 + 2], ndz[tid] * fs);
    }
}

// ---- node kernel: 64 nodes per block ----
template <bool BIG>
__global__ __launch_bounds__(256, 3) void node_kernel(
    const float* __restrict__ h, const unsigned short* __restrict__ hbf,
    const float* __restrict__ m_i,
    const unsigned short* __restrict__ mixbuf,
    const int* __restrict__ offsets, const int* __restrict__ counts,
    const unsigned short* __restrict__ Wn1T, const float* __restrict__ bn1,
    const unsigned short* __restrict__ Wn2T, const float* __restrict__ bn2,
    const float* __restrict__ ln_g, const float* __restrict__ ln_b,
    float* __restrict__ out_h) {
    __shared__ unsigned short Alds[64 * 264];
    __shared__ unsigned short mid1[64 * 136];

    const int tid = threadIdx.x;
    const int n0 = blockIdx.x * 64;

    if (BIG) {
        // CSR gather, now SEQUENTIAL in mixbuf: 4 threads/node, 32 cols each
        int ln = tid >> 2, q = tid & 3;
        int node = n0 + ln;
        if (node >= NN) node = NN - 1;
        float acc32[32];
#pragma unroll
        for (int i = 0; i < 32; i++) acc32[i] = 0.f;
        int beg = offsets[node], cnt = counts[node];
        for (int k = 0; k < cnt; k++) {
            const s16x8* p = (const s16x8*)&mixbuf[(size_t)(beg + k) * 128 + q * 32];
#pragma unroll
            for (int j = 0; j < 4; j++) {
                s16x8 v = p[j];
#pragma unroll
                for (int t = 0; t < 8; t++)
                    acc32[j * 8 + t] += bf2f((unsigned short)v[t]);
            }
        }
#pragma unroll
        for (int j = 0; j < 4; j++) {
            s16x8 s;
#pragma unroll
            for (int t = 0; t < 8; t++) s[t] = (short)f2bf(acc32[j * 8 + t]);
            *(s16x8*)&Alds[ln * 264 + 128 + q * 32 + j * 8] = s;
        }
        // h half: direct bf16 copies
#pragma unroll
        for (int j = 0; j < 4; j++)
            *(s16x8*)&Alds[ln * 264 + q * 32 + j * 8] =
                *(const s16x8*)&hbf[node * 128 + q * 32 + j * 8];
    } else {
        // stage A = [bf16(h) | bf16(m_i)]
#pragma unroll
        for (int i = 0; i < 8; i++) {
            int idx = tid + i * 256;
            int hr = idx >> 4, ch = idx & 15;
            int e = hr >> 1, half = hr & 1;
            int node = n0 + e;
            if (node >= NN) node = NN - 1;
            if (!half) {
                *(s16x8*)&Alds[e * 264 + ch * 8] =
                    *(const s16x8*)&hbf[node * 128 + ch * 8];
            } else {
                const f32x4* sp = (const f32x4*)&m_i[node * 128 + ch * 8];
                f32x4 f0 = sp[0], f1 = sp[1];
                s16x8 s;
#pragma unroll
                for (int j = 0; j < 4; j++) {
                    s[j] = (short)f2bf(f0[j]);
                    s[j + 4] = (short)f2bf(f1[j]);
                }
                *(s16x8*)&Alds[e * 264 + 128 + ch * 8] = s;
            }
        }
    }
    __syncthreads();

    const int lane = tid & 63;
    const int w = tid >> 6;
    const int ln15 = lane & 15;
    const int q8 = (lane >> 4) * 8, q4 = (lane >> 4) * 4;
    const int nbase = w * 32;

    f32x4 acc[4][2];

    // ---- layer n1: K=256
#pragma unroll
    for (int et = 0; et < 4; et++)
#pragma unroll
        for (int nt = 0; nt < 2; nt++) acc[et][nt] = (f32x4){0.f, 0.f, 0.f, 0.f};
#pragma unroll
    for (int kk = 0; kk < 8; kk++) {
        int k0 = kk * 32 + q8;
        s16x8 a[4], b[2];
#pragma unroll
        for (int et = 0; et < 4; et++)
            a[et] = *(const s16x8*)&Alds[(et * 16 + ln15) * 264 + k0];
#pragma unroll
        for (int nt = 0; nt < 2; nt++)
            b[nt] = *(const s16x8*)&Wn1T[(nbase + nt * 16 + ln15) * 256 + k0];
#pragma unroll
        for (int et = 0; et < 4; et++)
#pragma unroll
            for (int nt = 0; nt < 2; nt++)
                acc[et][nt] = __builtin_amdgcn_mfma_f32_16x16x32_bf16(
                    a[et], b[nt], acc[et][nt], 0, 0, 0);
    }
#pragma unroll
    for (int nt = 0; nt < 2; nt++) {
        int col = nbase + nt * 16 + ln15;
        float bias = bn1[col];
#pragma unroll
        for (int et = 0; et < 4; et++)
#pragma unroll
            for (int r = 0; r < 4; r++) {
                int row = et * 16 + q4 + r;
                mid1[row * 136 + col] = f2bf(silu(acc[et][nt][r] + bias));
            }
    }
    __syncthreads();

    // ---- layer n2: K=128, epilogue residual + stash f32 in tile
#pragma unroll
    for (int et = 0; et < 4; et++)
#pragma unroll
        for (int nt = 0; nt < 2; nt++) acc[et][nt] = (f32x4){0.f, 0.f, 0.f, 0.f};
#pragma unroll
    for (int kk = 0; kk < 4; kk++) {
        int k0 = kk * 32 + q8;
        s16x8 a[4], b[2];
#pragma unroll
        for (int et = 0; et < 4; et++)
            a[et] = *(const s16x8*)&mid1[(et * 16 + ln15) * 136 + k0];
#pragma unroll
        for (int nt = 0; nt < 2; nt++)
            b[nt] = *(const s16x8*)&Wn2T[(nbase + nt * 16 + ln15) * 128 + k0];
#pragma unroll
        for (int et = 0; et < 4; et++)
#pragma unroll
            for (int nt = 0; nt < 2; nt++)
                acc[et][nt] = __builtin_amdgcn_mfma_f32_16x16x32_bf16(
                    a[et], b[nt], acc[et][nt], 0, 0, 0);
    }
    __syncthreads();
    float* tile = (float*)Alds;  // [64][132] f32 = 33792 B, fits exactly
#pragma unroll
    for (int nt = 0; nt < 2; nt++) {
        int col = nbase + nt * 16 + ln15;
        float bias = bn2[col];
#pragma unroll
        for (int et = 0; et < 4; et++)
#pragma unroll
            for (int r = 0; r < 4; r++) {
                int row = et * 16 + q4 + r;
                int node = n0 + row;
                int nclamp = node >= NN ? NN - 1 : node;
                float v = acc[et][nt][r] + bias + h[nclamp * 128 + col];
                tile[row * 132 + col] = v;
            }
    }
    __syncthreads();

    // ---- LayerNorm: 4 threads per row, 32 cols each
    {
        int row = tid >> 2;
        int c0 = (tid & 3) * 32;
        float s = 0.f, s2 = 0.f;
#pragma unroll
        for (int c = 0; c < 32; c++) {
            float v = tile[row * 132 + c0 + c];
            s += v; s2 += v * v;
        }
        s += __shfl_xor(s, 1, 4);  s2 += __shfl_xor(s2, 1, 4);
        s += __shfl_xor(s, 2, 4);  s2 += __shfl_xor(s2, 2, 4);
        float mean = s * (1.f / 128.f);
        float var = s2 * (1.f / 128.f) - mean * mean;
        float rs = rsqrtf(var + 1e-5f);
        int node = n0 + row;
        if (node < NN) {
#pragma unroll
            for (int c = 0; c < 32; c++) {
                int col = c0 + c;
                float v = (tile[row * 132 + col] - mean) * rs * ln_g[col] + ln_b[col];
                out_h[node * 128 + col] = v;
            }
        }
    }
}

// ---- x update ----
__global__ void x_kernel(const float* __restrict__ x,
                         const float* __restrict__ x_acc,
                         float* __restrict__ out_x) {
    int i = blockIdx.x * 256 + threadIdx.x;
    if (i < NN * 3) out_x[i] = x[i] + x_acc[i];
}

extern "C" void kernel_launch(void* const* d_in, const int* in_sizes, int n_in,
                              void* d_out, int out_size, void* d_ws, size_t ws_size,
                              hipStream_t stream) {
    const float* h    = (const float*)d_in[0];
    const float* x    = (const float*)d_in[1];
    const int* eidx   = (const int*)d_in[2];
    const float* W_e1 = (const float*)d_in[3];
    const float* b_e1 = (const float*)d_in[4];
    const float* W_e2 = (const float*)d_in[5];
    const float* b_e2 = (const float*)d_in[6];
    const float* W_c1 = (const float*)d_in[7];
    const float* b_c1 = (const float*)d_in[8];
    const float* W_c2 = (const float*)d_in[9];
    const float* W_n1 = (const float*)d_in[10];
    const float* b_n1 = (const float*)d_in[11];
    const float* W_n2 = (const float*)d_in[12];
    const float* b_n2 = (const float*)d_in[13];
    const float* ln_g = (const float*)d_in[14];
    const float* ln_b = (const float*)d_in[15];

    float* out_h = (float*)d_out;
    float* out_x = out_h + NN * HH;

    const size_t NEEDED = 226000000;
    bool big = ws_size >= NEEDED;
    char* ws = (char*)d_ws;

    if (big) {
        unsigned short* mixbuf = (unsigned short*)ws;          // 204,800,000 B
        float* x_acc  = (float*)(ws + 204800000);              // 600,000 (zero)
        int* counts   = (int*)(ws + 205400000);                // 200,000 (zero)
        int* cursor   = (int*)(ws + 205600000);                // 200,000 (zero)
        int* offsets  = (int*)(ws + 205800000);                // 200,000
        int* partials = (int*)(ws + 206000000);                // 1,024
        int* scanp    = (int*)(ws + 206001024);                // 1,024
        int* rs       = (int*)(ws + 206002048);                // 3,200,000
        int* cs       = (int*)(ws + 209202048);                // 3,200,000
        unsigned short* hbf = (unsigned short*)(ws + 212402048);  // 12,800,000
        unsigned short* W1T  = (unsigned short*)(ws + 225202048);
        unsigned short* W2T  = W1T + 128 * 256;
        unsigned short* Wc1T = W2T + 128 * 128;
        unsigned short* Wn1T = Wc1T + 128 * 128;
        unsigned short* Wn2T = Wn1T + 128 * 256;

        hipMemsetAsync(ws + 204800000, 0, 1000000, stream);
        h2bf_k<<<(NN * HH / 8 + 255) / 256, 256, 0, stream>>>(h, hbf);
        transpose_w<<<(128 * 256 + 255) / 256, 256, 0, stream>>>(W_e1, W1T, 256);
        transpose_w<<<(128 * 128 + 255) / 256, 256, 0, stream>>>(W_e2, W2T, 128);
        transpose_w<<<(128 * 128 + 255) / 256, 256, 0, stream>>>(W_c1, Wc1T, 128);
        transpose_w<<<(128 * 256 + 255) / 256, 256, 0, stream>>>(W_n1, Wn1T, 256);
        transpose_w<<<(128 * 128 + 255) / 256, 256, 0, stream>>>(W_n2, Wn2T, 128);
        k_count<<<(NE + 255) / 256, 256, 0, stream>>>(eidx, counts);
        k_partial<<<SCAN_NB, 256, 0, stream>>>(counts, partials);
        k_scanp<<<1, 256, 0, stream>>>(partials, scanp);
        k_offsets<<<SCAN_NB, 256, 0, stream>>>(counts, scanp, offsets);
        k_fill<<<(NE + 255) / 256, 256, 0, stream>>>(eidx, offsets, cursor, rs, cs);

        edge_kernel<true><<<NE / 64, 256, 0, stream>>>(
            hbf, x, eidx, rs, cs, W1T, b_e1, W_e1, W2T, b_e2, Wc1T, b_c1, W_c2,
            nullptr, mixbuf, x_acc);
        node_kernel<true><<<(NN + 63) / 64, 256, 0, stream>>>(
            h, hbf, nullptr, mixbuf, offsets, counts, Wn1T, b_n1, Wn2T, b_n2,
            ln_g, ln_b, out_h);
        x_kernel<<<(NN * 3 + 255) / 256, 256, 0, stream>>>(x, x_acc, out_x);
    } else {
        float* m_i   = (float*)ws;                             // 25,600,000 (zero)
        float* x_acc = (float*)(ws + 25600000);                // 600,000 (zero)
        unsigned short* hbf = (unsigned short*)(ws + 26200000);  // 12,800,000
        unsigned short* W1T  = (unsigned short*)(ws + 39000000);
        unsigned short* W2T  = W1T + 128 * 256;
        unsigned short* Wc1T = W2T + 128 * 128;
        unsigned short* Wn1T = Wc1T + 128 * 128;
        unsigned short* Wn2T = Wn1T + 128 * 256;

        hipMemsetAsync(ws, 0, 26200000, stream);
        h2bf_k<<<(NN * HH / 8 + 255) / 256, 256, 0, stream>>>(h, hbf);
        transpose_w<<<(128 * 256 + 255) / 256, 256, 0, stream>>>(W_e1, W1T, 256);
        transpose_w<<<(128 * 128 + 255) / 256, 256, 0, stream>>>(W_e2, W2T, 128);
        transpose_w<<<(128 * 128 + 255) / 256, 256, 0, stream>>>(W_c1, Wc1T, 128);
        transpose_w<<<(128 * 256 + 255) / 256, 256, 0, stream>>>(W_n1, Wn1T, 256);
        transpose_w<<<(128 * 128 + 255) / 256, 256, 0, stream>>>(W_n2, Wn2T, 128);

        edge_kernel<false><<<NE / 64, 256, 0, stream>>>(
            hbf, x, eidx, nullptr, nullptr, W1T, b_e1, W_e1, W2T, b_e2, Wc1T,
            b_c1, W_c2, m_i, nullptr, x_acc);
        node_kernel<false><<<(NN + 63) / 64, 256, 0, stream>>>(
            h, hbf, m_i, nullptr, nullptr, nullptr, Wn1T, b_n1, Wn2T, b_n2,
            ln_g, ln_b, out_h);
        x_kernel<<<(NN * 3 + 255) / 256, 256, 0, stream>>>(x, x_acc, out_x);
    }
}

// Round 5
// 668.274 us; speedup vs baseline: 1.0704x; 1.0704x over previous
//
#include <hip/hip_runtime.h>
#include <hip/hip_bf16.h>

#define NN 50000
#define NE 800000
#define HH 128
#define SCAN_NB 196  // ceil(50000/256)

typedef short s16x8 __attribute__((ext_vector_type(8)));
typedef float f32x4 __attribute__((ext_vector_type(4)));

__device__ __forceinline__ float bf2f(unsigned short u) {
    unsigned int v = ((unsigned int)u) << 16;
    float f;
    __builtin_memcpy(&f, &v, 4);
    return f;
}
__device__ __forceinline__ unsigned short f2bf(float f) {
    unsigned int x;
    __builtin_memcpy(&x, &f, 4);
    unsigned int r = (x + 0x7fffu + ((x >> 16) & 1u)) >> 16;
    return (unsigned short)r;
}
__device__ __forceinline__ float silu(float v) { return v / (1.f + __expf(-v)); }

// ---- h f32 -> bf16 pre-pass ----
__global__ void h2bf_k(const float* __restrict__ h, unsigned short* __restrict__ hbf) {
    int i = blockIdx.x * 256 + threadIdx.x;  // one per 8 elems
    if (i >= NN * HH / 8) return;
    const f32x4* p = (const f32x4*)&h[i * 8];
    f32x4 a = p[0], b = p[1];
    s16x8 s;
#pragma unroll
    for (int j = 0; j < 4; j++) {
        s[j] = (short)f2bf(a[j]);
        s[j + 4] = (short)f2bf(b[j]);
    }
    *(s16x8*)&hbf[i * 8] = s;
}

// ---- weight transpose+cast: W[k][128] f32 -> WT[n][K] bf16 ----
__global__ void transpose_w(const float* __restrict__ W,
                            unsigned short* __restrict__ WT, int K) {
    int idx = blockIdx.x * 256 + threadIdx.x;
    if (idx >= 128 * K) return;
    int n = idx / K, k = idx - n * K;
    WT[idx] = f2bf(W[k * 128 + n]);
}

// ---- CSR build ----
__global__ void k_count(const int* __restrict__ eidx, int* __restrict__ counts) {
    int e = blockIdx.x * 256 + threadIdx.x;
    if (e >= NE) return;
    int r = eidx[e];
    r = r < 0 ? 0 : (r >= NN ? NN - 1 : r);
    atomicAdd(&counts[r], 1);
}
__global__ void k_partial(const int* __restrict__ counts, int* __restrict__ partials) {
    __shared__ int sm[256];
    int idx = blockIdx.x * 256 + threadIdx.x;
    sm[threadIdx.x] = idx < NN ? counts[idx] : 0;
    __syncthreads();
    for (int s = 128; s > 0; s >>= 1) {
        if (threadIdx.x < s) sm[threadIdx.x] += sm[threadIdx.x + s];
        __syncthreads();
    }
    if (threadIdx.x == 0) partials[blockIdx.x] = sm[0];
}
__global__ void k_scanp(const int* __restrict__ partials, int* __restrict__ scanp) {
    __shared__ int sm[256];
    int t = threadIdx.x;
    int v = t < SCAN_NB ? partials[t] : 0;
    sm[t] = v;
    __syncthreads();
    for (int d = 1; d < 256; d <<= 1) {
        int add = t >= d ? sm[t - d] : 0;
        __syncthreads();
        sm[t] += add;
        __syncthreads();
    }
    scanp[t] = sm[t] - v;  // exclusive
}
__global__ void k_offsets(const int* __restrict__ counts, const int* __restrict__ scanp,
                          int* __restrict__ offsets) {
    __shared__ int sm[256];
    int t = threadIdx.x, idx = blockIdx.x * 256 + t;
    int v = idx < NN ? counts[idx] : 0;
    sm[t] = v;
    __syncthreads();
    for (int d = 1; d < 256; d <<= 1) {
        int add = t >= d ? sm[t - d] : 0;
        __syncthreads();
        sm[t] += add;
        __syncthreads();
    }
    if (idx < NN) offsets[idx] = sm[t] - v + scanp[blockIdx.x];
}
// sort edges into CSR slot order: rs/cs indexed by slot
__global__ void k_fill(const int* __restrict__ eidx, const int* __restrict__ offsets,
                       int* __restrict__ cursor, int* __restrict__ rs,
                       int* __restrict__ cs) {
    int e = blockIdx.x * 256 + threadIdx.x;
    if (e >= NE) return;
    int r = eidx[e];
    int c = eidx[NE + e];
    r = r < 0 ? 0 : (r >= NN ? NN - 1 : r);
    c = c < 0 ? 0 : (c >= NN ? NN - 1 : c);
    int slot = offsets[r] + atomicAdd(&cursor[r], 1);
    rs[slot] = r;
    cs[slot] = c;
}

// ---- edge kernel: 64 edge-slots per block, 4 waves, 4 blocks/CU ----
// BIG: CSR-sorted slots via rs/cs; m_ij bf16 -> mixbuf; force -> fbuf (if set)
// !BIG: natural edge order; atomicAdd m_i; atomicAdd x_acc.
template <bool BIG>
__global__ __launch_bounds__(256, 4) void edge_kernel(
    const unsigned short* __restrict__ hbf, const float* __restrict__ x,
    const int* __restrict__ eidx, const int* __restrict__ rs,
    const int* __restrict__ cs,
    const unsigned short* __restrict__ W1T, const float* __restrict__ b1,
    const float* __restrict__ W1full,  // [257][128] f32, row 256 = radial row
    const unsigned short* __restrict__ W2T, const float* __restrict__ b2,
    const unsigned short* __restrict__ Wc1T, const float* __restrict__ bc1,
    const float* __restrict__ wc2,
    float* __restrict__ m_i, unsigned short* __restrict__ mixbuf,
    float* __restrict__ fbuf, float* __restrict__ x_acc) {
    // A tile [64][264] bf16 = 33792 B. After e1 k-loop A is dead:
    // mid1 aliases shorts [0, 64*132), mid2 aliases [64*132, 64*264).
    __shared__ unsigned short Alds[64 * 264];
    unsigned short* mid1 = Alds;
    unsigned short* mid2 = Alds + 64 * 132;
    __shared__ float rad[64], ndx[64], ndy[64], ndz[64], fsum[64];
    __shared__ int rowA[64], colA[64];

    const int tid = threadIdx.x;
    const int e0 = blockIdx.x * 64;

    if (tid < 64) {
        int r, c;
        if (BIG) {
            r = rs[e0 + tid];
            c = cs[e0 + tid];
        } else {
            r = eidx[e0 + tid];
            c = eidx[NE + e0 + tid];
            r = r < 0 ? 0 : (r >= NN ? NN - 1 : r);
            c = c < 0 ? 0 : (c >= NN ? NN - 1 : c);
        }
        rowA[tid] = r; colA[tid] = c;
        float dx = x[r * 3 + 0] - x[c * 3 + 0];
        float dy = x[r * 3 + 1] - x[c * 3 + 1];
        float dz = x[r * 3 + 2] - x[c * 3 + 2];
        float d2 = dx * dx + dy * dy + dz * dz;
        float dist = sqrtf(d2);
        float inv = 1.f / (dist + 1e-8f);
        rad[tid] = d2;
        ndx[tid] = dx * inv; ndy[tid] = dy * inv; ndz[tid] = dz * inv;
        fsum[tid] = 0.f;
    }
    __syncthreads();

    // stage A = [hbf[row] | hbf[col]] : pure 16B copies
#pragma unroll
    for (int i = 0; i < 8; i++) {
        int idx = tid + i * 256;
        int hr = idx >> 4, ch = idx & 15;
        int e = hr >> 1, half = hr & 1;
        int node = half ? colA[e] : rowA[e];
        *(s16x8*)&Alds[e * 264 + half * 128 + ch * 8] =
            *(const s16x8*)&hbf[node * 128 + ch * 8];
    }
    __syncthreads();

    const int lane = tid & 63;
    const int w = tid >> 6;
    const int ln15 = lane & 15;
    const int q8 = (lane >> 4) * 8, q4 = (lane >> 4) * 4;
    const int nbase = w * 32;

    f32x4 acc[4][2];

    // ---- layer e1: [64x256]@W1 + bias + radial*W1[256], silu -> mid1
#pragma unroll
    for (int et = 0; et < 4; et++)
#pragma unroll
        for (int nt = 0; nt < 2; nt++) acc[et][nt] = (f32x4){0.f, 0.f, 0.f, 0.f};
#pragma unroll
    for (int kk = 0; kk < 8; kk++) {
        int k0 = kk * 32 + q8;
        s16x8 a[4], b[2];
#pragma unroll
        for (int et = 0; et < 4; et++)
            a[et] = *(const s16x8*)&Alds[(et * 16 + ln15) * 264 + k0];
#pragma unroll
        for (int nt = 0; nt < 2; nt++)
            b[nt] = *(const s16x8*)&W1T[(nbase + nt * 16 + ln15) * 256 + k0];
#pragma unroll
        for (int et = 0; et < 4; et++)
#pragma unroll
            for (int nt = 0; nt < 2; nt++)
                acc[et][nt] = __builtin_amdgcn_mfma_f32_16x16x32_bf16(
                    a[et], b[nt], acc[et][nt], 0, 0, 0);
    }
    __syncthreads();  // A dead; mid1 may overwrite it
#pragma unroll
    for (int nt = 0; nt < 2; nt++) {
        int col = nbase + nt * 16 + ln15;
        float bias = b1[col];
        float wlast = W1full[256 * 128 + col];
#pragma unroll
        for (int et = 0; et < 4; et++)
#pragma unroll
            for (int r = 0; r < 4; r++) {
                int row = et * 16 + q4 + r;
                float v = acc[et][nt][r] + bias + rad[row] * wlast;
                mid1[row * 132 + col] = f2bf(silu(v));
            }
    }
    __syncthreads();

    // ---- layer e2: silu([64x128]@W2 + b2) = m_ij -> mid2 (+ atomics if !BIG)
#pragma unroll
    for (int et = 0; et < 4; et++)
#pragma unroll
        for (int nt = 0; nt < 2; nt++) acc[et][nt] = (f32x4){0.f, 0.f, 0.f, 0.f};
#pragma unroll
    for (int kk = 0; kk < 4; kk++) {
        int k0 = kk * 32 + q8;
        s16x8 a[4], b[2];
#pragma unroll
        for (int et = 0; et < 4; et++)
            a[et] = *(const s16x8*)&mid1[(et * 16 + ln15) * 132 + k0];
#pragma unroll
        for (int nt = 0; nt < 2; nt++)
            b[nt] = *(const s16x8*)&W2T[(nbase + nt * 16 + ln15) * 128 + k0];
#pragma unroll
        for (int et = 0; et < 4; et++)
#pragma unroll
            for (int nt = 0; nt < 2; nt++)
                acc[et][nt] = __builtin_amdgcn_mfma_f32_16x16x32_bf16(
                    a[et], b[nt], acc[et][nt], 0, 0, 0);
    }
#pragma unroll
    for (int nt = 0; nt < 2; nt++) {
        int col = nbase + nt * 16 + ln15;
        float bias = b2[col];
#pragma unroll
        for (int et = 0; et < 4; et++)
#pragma unroll
            for (int r = 0; r < 4; r++) {
                int row = et * 16 + q4 + r;
                float v = silu(acc[et][nt][r] + bias);
                if (!BIG) atomicAdd(&m_i[rowA[row] * 128 + col], v);
                mid2[row * 132 + col] = f2bf(v);
            }
    }
    __syncthreads();

    // ---- coord layer: c1 = silu(m_ij @ Wc1 + bc1); fs = tanh(c1.wc2)*0.1
#pragma unroll
    for (int et = 0; et < 4; et++)
#pragma unroll
        for (int nt = 0; nt < 2; nt++) acc[et][nt] = (f32x4){0.f, 0.f, 0.f, 0.f};
#pragma unroll
    for (int kk = 0; kk < 4; kk++) {
        int k0 = kk * 32 + q8;
        s16x8 a[4], b[2];
#pragma unroll
        for (int et = 0; et < 4; et++)
            a[et] = *(const s16x8*)&mid2[(et * 16 + ln15) * 132 + k0];
#pragma unroll
        for (int nt = 0; nt < 2; nt++)
            b[nt] = *(const s16x8*)&Wc1T[(nbase + nt * 16 + ln15) * 128 + k0];
#pragma unroll
        for (int et = 0; et < 4; et++)
#pragma unroll
            for (int nt = 0; nt < 2; nt++)
                acc[et][nt] = __builtin_amdgcn_mfma_f32_16x16x32_bf16(
                    a[et], b[nt], acc[et][nt], 0, 0, 0);
    }

    if (BIG) {  // coalesced, CSR-ordered m_ij export (mid2 read-only now)
#pragma unroll
        for (int j = 0; j < 4; j++) {
            int c = tid + j * 256;
            int row = c >> 4, ch = c & 15;
            *(s16x8*)&mixbuf[(size_t)(e0 + row) * 128 + ch * 8] =
                *(s16x8*)&mid2[row * 132 + ch * 8];
        }
    }

    {
        float part[4][4];
#pragma unroll
        for (int et = 0; et < 4; et++)
#pragma unroll
            for (int r = 0; r < 4; r++) part[et][r] = 0.f;
#pragma unroll
        for (int nt = 0; nt < 2; nt++) {
            int col = nbase + nt * 16 + ln15;
            float bias = bc1[col];
            float w2 = wc2[col];
#pragma unroll
            for (int et = 0; et < 4; et++)
#pragma unroll
                for (int r = 0; r < 4; r++)
                    part[et][r] += silu(acc[et][nt][r] + bias) * w2;
        }
#pragma unroll
        for (int et = 0; et < 4; et++)
#pragma unroll
            for (int r = 0; r < 4; r++) {
                float p = part[et][r];
                p += __shfl_xor(p, 8, 16);
                p += __shfl_xor(p, 4, 16);
                p += __shfl_xor(p, 2, 16);
                p += __shfl_xor(p, 1, 16);
                if (ln15 == 0) atomicAdd(&fsum[et * 16 + q4 + r], p);
            }
    }
    __syncthreads();
    if (tid < 64) {
        float fs = tanhf(fsum[tid]) * 0.1f;
        if (BIG && fbuf) {  // per-edge force, summed later by x_gather (no atomics)
            fbuf[(size_t)(e0 + tid) * 3 + 0] = ndx[tid] * fs;
            fbuf[(size_t)(e0 + tid) * 3 + 1] = ndy[tid] * fs;
            fbuf[(size_t)(e0 + tid) * 3 + 2] = ndz[tid] * fs;
        } else {
            int rn = rowA[tid];
            atomicAdd(&x_acc[rn * 3 + 0], ndx[tid] * fs);
            atomicAdd(&x_acc[rn * 3 + 1], ndy[tid] * fs);
            atomicAdd(&x_acc[rn * 3 + 2], ndz[tid] * fs);
        }
    }
}

// ---- node kernel: 64 nodes per block, 4 blocks/CU ----
template <bool BIG>
__global__ __launch_bounds__(256, 4) void node_kernel(
    const float* __restrict__ h, const unsigned short* __restrict__ hbf,
    const float* __restrict__ m_i,
    const unsigned short* __restrict__ mixbuf,
    const int* __restrict__ offsets, const int* __restrict__ counts,
    const unsigned short* __restrict__ Wn1T, const float* __restrict__ bn1,
    const unsigned short* __restrict__ Wn2T, const float* __restrict__ bn2,
    const float* __restrict__ ln_g, const float* __restrict__ ln_b,
    float* __restrict__ out_h) {
    // A tile [64][264] bf16; after n1: mid1 aliases [0,64*132) shorts;
    // after n2: tile f32 [64][132] aliases the whole block.
    __shared__ unsigned short Alds[64 * 264];
    unsigned short* mid1 = Alds;
    float* tile = (float*)Alds;

    const int tid = threadIdx.x;
    const int n0 = blockIdx.x * 64;

    if (BIG) {
        // CSR gather, sequential in mixbuf: 4 threads/node, 32 cols each
        int ln = tid >> 2, q = tid & 3;
        int node = n0 + ln;
        if (node >= NN) node = NN - 1;
        float acc32[32];
#pragma unroll
        for (int i = 0; i < 32; i++) acc32[i] = 0.f;
        int beg = offsets[node], cnt = counts[node];
        for (int k = 0; k < cnt; k++) {
            const s16x8* p = (const s16x8*)&mixbuf[(size_t)(beg + k) * 128 + q * 32];
#pragma unroll
            for (int j = 0; j < 4; j++) {
                s16x8 v = p[j];
#pragma unroll
                for (int t = 0; t < 8; t++)
                    acc32[j * 8 + t] += bf2f((unsigned short)v[t]);
            }
        }
#pragma unroll
        for (int j = 0; j < 4; j++) {
            s16x8 s;
#pragma unroll
            for (int t = 0; t < 8; t++) s[t] = (short)f2bf(acc32[j * 8 + t]);
            *(s16x8*)&Alds[ln * 264 + 128 + q * 32 + j * 8] = s;
        }
#pragma unroll
        for (int j = 0; j < 4; j++)
            *(s16x8*)&Alds[ln * 264 + q * 32 + j * 8] =
                *(const s16x8*)&hbf[node * 128 + q * 32 + j * 8];
    } else {
#pragma unroll
        for (int i = 0; i < 8; i++) {
            int idx = tid + i * 256;
            int hr = idx >> 4, ch = idx & 15;
            int e = hr >> 1, half = hr & 1;
            int node = n0 + e;
            if (node >= NN) node = NN - 1;
            if (!half) {
                *(s16x8*)&Alds[e * 264 + ch * 8] =
                    *(const s16x8*)&hbf[node * 128 + ch * 8];
            } else {
                const f32x4* sp = (const f32x4*)&m_i[node * 128 + ch * 8];
                f32x4 f0 = sp[0], f1 = sp[1];
                s16x8 s;
#pragma unroll
                for (int j = 0; j < 4; j++) {
                    s[j] = (short)f2bf(f0[j]);
                    s[j + 4] = (short)f2bf(f1[j]);
                }
                *(s16x8*)&Alds[e * 264 + 128 + ch * 8] = s;
            }
        }
    }
    __syncthreads();

    const int lane = tid & 63;
    const int w = tid >> 6;
    const int ln15 = lane & 15;
    const int q8 = (lane >> 4) * 8, q4 = (lane >> 4) * 4;
    const int nbase = w * 32;

    f32x4 acc[4][2];

    // ---- layer n1: K=256
#pragma unroll
    for (int et = 0; et < 4; et++)
#pragma unroll
        for (int nt = 0; nt < 2; nt++) acc[et][nt] = (f32x4){0.f, 0.f, 0.f, 0.f};
#pragma unroll
    for (int kk = 0; kk < 8; kk++) {
        int k0 = kk * 32 + q8;
        s16x8 a[4], b[2];
#pragma unroll
        for (int et = 0; et < 4; et++)
            a[et] = *(const s16x8*)&Alds[(et * 16 + ln15) * 264 + k0];
#pragma unroll
        for (int nt = 0; nt < 2; nt++)
            b[nt] = *(const s16x8*)&Wn1T[(nbase + nt * 16 + ln15) * 256 + k0];
#pragma unroll
        for (int et = 0; et < 4; et++)
#pragma unroll
            for (int nt = 0; nt < 2; nt++)
                acc[et][nt] = __builtin_amdgcn_mfma_f32_16x16x32_bf16(
                    a[et], b[nt], acc[et][nt], 0, 0, 0);
    }
    __syncthreads();  // A dead; mid1 may overwrite it
#pragma unroll
    for (int nt = 0; nt < 2; nt++) {
        int col = nbase + nt * 16 + ln15;
        float bias = bn1[col];
#pragma unroll
        for (int et = 0; et < 4; et++)
#pragma unroll
            for (int r = 0; r < 4; r++) {
                int row = et * 16 + q4 + r;
                mid1[row * 132 + col] = f2bf(silu(acc[et][nt][r] + bias));
            }
    }
    __syncthreads();

    // ---- layer n2: K=128, epilogue residual + stash f32 in tile
#pragma unroll
    for (int et = 0; et < 4; et++)
#pragma unroll
        for (int nt = 0; nt < 2; nt++) acc[et][nt] = (f32x4){0.f, 0.f, 0.f, 0.f};
#pragma unroll
    for (int kk = 0; kk < 4; kk++) {
        int k0 = kk * 32 + q8;
        s16x8 a[4], b[2];
#pragma unroll
        for (int et = 0; et < 4; et++)
            a[et] = *(const s16x8*)&mid1[(et * 16 + ln15) * 132 + k0];
#pragma unroll
        for (int nt = 0; nt < 2; nt++)
            b[nt] = *(const s16x8*)&Wn2T[(nbase + nt * 16 + ln15) * 128 + k0];
#pragma unroll
        for (int et = 0; et < 4; et++)
#pragma unroll
            for (int nt = 0; nt < 2; nt++)
                acc[et][nt] = __builtin_amdgcn_mfma_f32_16x16x32_bf16(
                    a[et], b[nt], acc[et][nt], 0, 0, 0);
    }
    __syncthreads();  // mid1 dead; f32 tile may overwrite
#pragma unroll
    for (int nt = 0; nt < 2; nt++) {
        int col = nbase + nt * 16 + ln15;
        float bias = bn2[col];
#pragma unroll
        for (int et = 0; et < 4; et++)
#pragma unroll
            for (int r = 0; r < 4; r++) {
                int row = et * 16 + q4 + r;
                int node = n0 + row;
                int nclamp = node >= NN ? NN - 1 : node;
                float v = acc[et][nt][r] + bias + h[nclamp * 128 + col];
                tile[row * 132 + col] = v;
            }
    }
    __syncthreads();

    // ---- LayerNorm: 4 threads/row, interleaved cols (q, q+4, ...)
    {
        int row = tid >> 2;
        int q = tid & 3;
        float s = 0.f, s2 = 0.f;
#pragma unroll
        for (int c = 0; c < 32; c++) {
            float v = tile[row * 132 + q + c * 4];
            s += v; s2 += v * v;
        }
        s += __shfl_xor(s, 1, 4);  s2 += __shfl_xor(s2, 1, 4);
        s += __shfl_xor(s, 2, 4);  s2 += __shfl_xor(s2, 2, 4);
        float mean = s * (1.f / 128.f);
        float var = s2 * (1.f / 128.f) - mean * mean;
        float rs = rsqrtf(var + 1e-5f);
        int node = n0 + row;
        if (node < NN) {
#pragma unroll
            for (int c = 0; c < 32; c++) {
                int col = q + c * 4;
                float v = (tile[row * 132 + col] - mean) * rs * ln_g[col] + ln_b[col];
                out_h[node * 128 + col] = v;
            }
        }
    }
}

// ---- x update: CSR sweep over per-edge forces (no atomics) ----
__global__ void x_gather(const float* __restrict__ x, const float* __restrict__ fbuf,
                         const int* __restrict__ offsets,
                         const int* __restrict__ counts, float* __restrict__ out_x) {
    int n = blockIdx.x * 256 + threadIdx.x;
    if (n >= NN) return;
    int beg = offsets[n], cnt = counts[n];
    float ax = 0.f, ay = 0.f, az = 0.f;
    for (int k = 0; k < cnt; k++) {
        const float* p = &fbuf[(size_t)(beg + k) * 3];
        ax += p[0]; ay += p[1]; az += p[2];
    }
    out_x[n * 3 + 0] = x[n * 3 + 0] + ax;
    out_x[n * 3 + 1] = x[n * 3 + 1] + ay;
    out_x[n * 3 + 2] = x[n * 3 + 2] + az;
}

// ---- x update from atomic accumulator ----
__global__ void x_kernel(const float* __restrict__ x,
                         const float* __restrict__ x_acc,
                         float* __restrict__ out_x) {
    int i = blockIdx.x * 256 + threadIdx.x;
    if (i < NN * 3) out_x[i] = x[i] + x_acc[i];
}

extern "C" void kernel_launch(void* const* d_in, const int* in_sizes, int n_in,
                              void* d_out, int out_size, void* d_ws, size_t ws_size,
                              hipStream_t stream) {
    const float* h    = (const float*)d_in[0];
    const float* x    = (const float*)d_in[1];
    const int* eidx   = (const int*)d_in[2];
    const float* W_e1 = (const float*)d_in[3];
    const float* b_e1 = (const float*)d_in[4];
    const float* W_e2 = (const float*)d_in[5];
    const float* b_e2 = (const float*)d_in[6];
    const float* W_c1 = (const float*)d_in[7];
    const float* b_c1 = (const float*)d_in[8];
    const float* W_c2 = (const float*)d_in[9];
    const float* W_n1 = (const float*)d_in[10];
    const float* b_n1 = (const float*)d_in[11];
    const float* W_n2 = (const float*)d_in[12];
    const float* b_n2 = (const float*)d_in[13];
    const float* ln_g = (const float*)d_in[14];
    const float* ln_b = (const float*)d_in[15];

    float* out_h = (float*)d_out;
    float* out_x = out_h + NN * HH;

    const size_t NEED_BASE = 226000000;   // big path without fbuf
    const size_t NEED_FB   = 235100000;   // big path + fbuf
    bool big = ws_size >= NEED_BASE;
    bool use_fb = ws_size >= NEED_FB;
    char* ws = (char*)d_ws;

    if (big) {
        unsigned short* mixbuf = (unsigned short*)ws;          // 204,800,000 B
        float* x_acc  = (float*)(ws + 204800000);              // 600,000 (zero)
        int* counts   = (int*)(ws + 205400000);                // 200,000 (zero)
        int* cursor   = (int*)(ws + 205600000);                // 200,000 (zero)
        int* offsets  = (int*)(ws + 205800000);                // 200,000
        int* partials = (int*)(ws + 206000000);                // 1,024
        int* scanp    = (int*)(ws + 206001024);                // 1,024
        int* rs       = (int*)(ws + 206002048);                // 3,200,000
        int* cs       = (int*)(ws + 209202048);                // 3,200,000
        unsigned short* hbf = (unsigned short*)(ws + 212402048);  // 12,800,000
        unsigned short* W1T  = (unsigned short*)(ws + 225202048); // 229,376 total
        unsigned short* W2T  = W1T + 128 * 256;
        unsigned short* Wc1T = W2T + 128 * 128;
        unsigned short* Wn1T = Wc1T + 128 * 128;
        unsigned short* Wn2T = Wn1T + 128 * 256;
        float* fbuf = use_fb ? (float*)(ws + 225431424) : nullptr;  // 9,600,000

        hipMemsetAsync(ws + 204800000, 0, 1000000, stream);
        h2bf_k<<<(NN * HH / 8 + 255) / 256, 256, 0, stream>>>(h, hbf);
        transpose_w<<<(128 * 256 + 255) / 256, 256, 0, stream>>>(W_e1, W1T, 256);
        transpose_w<<<(128 * 128 + 255) / 256, 256, 0, stream>>>(W_e2, W2T, 128);
        transpose_w<<<(128 * 128 + 255) / 256, 256, 0, stream>>>(W_c1, Wc1T, 128);
        transpose_w<<<(128 * 256 + 255) / 256, 256, 0, stream>>>(W_n1, Wn1T, 256);
        transpose_w<<<(128 * 128 + 255) / 256, 256, 0, stream>>>(W_n2, Wn2T, 128);
        k_count<<<(NE + 255) / 256, 256, 0, stream>>>(eidx, counts);
        k_partial<<<SCAN_NB, 256, 0, stream>>>(counts, partials);
        k_scanp<<<1, 256, 0, stream>>>(partials, scanp);
        k_offsets<<<SCAN_NB, 256, 0, stream>>>(counts, scanp, offsets);
        k_fill<<<(NE + 255) / 256, 256, 0, stream>>>(eidx, offsets, cursor, rs, cs);

        edge_kernel<true><<<NE / 64, 256, 0, stream>>>(
            hbf, x, eidx, rs, cs, W1T, b_e1, W_e1, W2T, b_e2, Wc1T, b_c1, W_c2,
            nullptr, mixbuf, fbuf, x_acc);
        node_kernel<true><<<(NN + 63) / 64, 256, 0, stream>>>(
            h, hbf, nullptr, mixbuf, offsets, counts, Wn1T, b_n1, Wn2T, b_n2,
            ln_g, ln_b, out_h);
        if (use_fb)
            x_gather<<<(NN + 255) / 256, 256, 0, stream>>>(x, fbuf, offsets,
                                                           counts, out_x);
        else
            x_kernel<<<(NN * 3 + 255) / 256, 256, 0, stream>>>(x, x_acc, out_x);
    } else {
        float* m_i   = (float*)ws;                             // 25,600,000 (zero)
        float* x_acc = (float*)(ws + 25600000);                // 600,000 (zero)
        unsigned short* hbf = (unsigned short*)(ws + 26200000);  // 12,800,000
        unsigned short* W1T  = (unsigned short*)(ws + 39000000);
        unsigned short* W2T  = W1T + 128 * 256;
        unsigned short* Wc1T = W2T + 128 * 128;
        unsigned short* Wn1T = Wc1T + 128 * 128;
        unsigned short* Wn2T = Wn1T + 128 * 256;

        hipMemsetAsync(ws, 0, 26200000, stream);
        h2bf_k<<<(NN * HH / 8 + 255) / 256, 256, 0, stream>>>(h, hbf);
        transpose_w<<<(128 * 256 + 255) / 256, 256, 0, stream>>>(W_e1, W1T, 256);
        transpose_w<<<(128 * 128 + 255) / 256, 256, 0, stream>>>(W_e2, W2T, 128);
        transpose_w<<<(128 * 128 + 255) / 256, 256, 0, stream>>>(W_c1, Wc1T, 128);
        transpose_w<<<(128 * 256 + 255) / 256, 256, 0, stream>>>(W_n1, Wn1T, 256);
        transpose_w<<<(128 * 128 + 255) / 256, 256, 0, stream>>>(W_n2, Wn2T, 128);

        edge_kernel<false><<<NE / 64, 256, 0, stream>>>(
            hbf, x, eidx, nullptr, nullptr, W1T, b_e1, W_e1, W2T, b_e2, Wc1T,
            b_c1, W_c2, m_i, nullptr, nullptr, x_acc);
        node_kernel<false><<<(NN + 63) / 64, 256, 0, stream>>>(
            h, hbf, m_i, nullptr, nullptr, nullptr, Wn1T, b_n1, Wn2T, b_n2,
            ln_g, ln_b, out_h);
        x_kernel<<<(NN * 3 + 255) / 256, 256, 0, stream>>>(x, x_acc, out_x);
    }
}

// Round 6
// 490.152 us; speedup vs baseline: 1.4594x; 1.3634x over previous
//
#include <hip/hip_runtime.h>
#include <hip/hip_bf16.h>

#define NN 50000
#define NE 800000
#define HH 128
#define SCAN_NB 196  // ceil(50000/256)

typedef short s16x8 __attribute__((ext_vector_type(8)));
typedef float f32x4 __attribute__((ext_vector_type(4)));

__device__ __forceinline__ float bf2f(unsigned short u) {
    unsigned int v = ((unsigned int)u) << 16;
    float f;
    __builtin_memcpy(&f, &v, 4);
    return f;
}
__device__ __forceinline__ unsigned short f2bf(float f) {
    unsigned int x;
    __builtin_memcpy(&x, &f, 4);
    unsigned int r = (x + 0x7fffu + ((x >> 16) & 1u)) >> 16;
    return (unsigned short)r;
}
__device__ __forceinline__ float silu(float v) { return v / (1.f + __expf(-v)); }

// ---- weight transpose+cast: W[k][128] f32 -> WT[n][K] bf16 ----
__global__ void transpose_w(const float* __restrict__ W,
                            unsigned short* __restrict__ WT, int K) {
    int idx = blockIdx.x * 256 + threadIdx.x;
    if (idx >= 128 * K) return;
    int n = idx / K, k = idx - n * K;
    WT[idx] = f2bf(W[k * 128 + n]);
}

// ---- PWT[c'][k]: c'<128 -> W_e1[k][c'] (W_top^T), else W_e1[128+k][c'-128] ----
__global__ void transpose_pw(const float* __restrict__ W1,
                             unsigned short* __restrict__ PWT) {
    int idx = blockIdx.x * 256 + threadIdx.x;
    if (idx >= 256 * 128) return;
    int cp = idx >> 7, k = idx & 127;
    int srow = (cp < 128) ? k : (128 + k);
    int scol = cp & 127;
    PWT[idx] = f2bf(W1[srow * 128 + scol]);
}

// ---- CSR build ----
__global__ void k_count(const int* __restrict__ eidx, int* __restrict__ counts) {
    int e = blockIdx.x * 256 + threadIdx.x;
    if (e >= NE) return;
    int r = eidx[e];
    r = r < 0 ? 0 : (r >= NN ? NN - 1 : r);
    atomicAdd(&counts[r], 1);
}
__global__ void k_partial(const int* __restrict__ counts, int* __restrict__ partials) {
    __shared__ int sm[256];
    int idx = blockIdx.x * 256 + threadIdx.x;
    sm[threadIdx.x] = idx < NN ? counts[idx] : 0;
    __syncthreads();
    for (int s = 128; s > 0; s >>= 1) {
        if (threadIdx.x < s) sm[threadIdx.x] += sm[threadIdx.x + s];
        __syncthreads();
    }
    if (threadIdx.x == 0) partials[blockIdx.x] = sm[0];
}
__global__ void k_scanp(const int* __restrict__ partials, int* __restrict__ scanp) {
    __shared__ int sm[256];
    int t = threadIdx.x;
    int v = t < SCAN_NB ? partials[t] : 0;
    sm[t] = v;
    __syncthreads();
    for (int d = 1; d < 256; d <<= 1) {
        int add = t >= d ? sm[t - d] : 0;
        __syncthreads();
        sm[t] += add;
        __syncthreads();
    }
    scanp[t] = sm[t] - v;  // exclusive
}
__global__ void k_offsets(const int* __restrict__ counts, const int* __restrict__ scanp,
                          int* __restrict__ offsets) {
    __shared__ int sm[256];
    int t = threadIdx.x, idx = blockIdx.x * 256 + t;
    int v = idx < NN ? counts[idx] : 0;
    sm[t] = v;
    __syncthreads();
    for (int d = 1; d < 256; d <<= 1) {
        int add = t >= d ? sm[t - d] : 0;
        __syncthreads();
        sm[t] += add;
        __syncthreads();
    }
    if (idx < NN) offsets[idx] = sm[t] - v + scanp[blockIdx.x];
}
// sort edges into CSR slot order; pack (r,c) as u16 pair (NN < 65536)
__global__ void k_fill(const int* __restrict__ eidx, const int* __restrict__ offsets,
                       int* __restrict__ cursor, unsigned int* __restrict__ rc) {
    int e = blockIdx.x * 256 + threadIdx.x;
    if (e >= NE) return;
    int r = eidx[e];
    int c = eidx[NE + e];
    r = r < 0 ? 0 : (r >= NN ? NN - 1 : r);
    c = c < 0 ? 0 : (c >= NN ? NN - 1 : c);
    int slot = offsets[r] + atomicAdd(&cursor[r], 1);
    rc[slot] = (unsigned int)r | ((unsigned int)c << 16);
}

// ---- P-GEMM: P1 = bf16(h) @ W_top, P2 = bf16(h) @ W_bot (bf16 out) ----
__global__ __launch_bounds__(256, 4) void pgemm(
    const float* __restrict__ h, const unsigned short* __restrict__ PWT,
    unsigned short* __restrict__ P1, unsigned short* __restrict__ P2) {
    __shared__ unsigned short Alds[64 * 136];
    const int tid = threadIdx.x;
    const int n0 = blockIdx.x * 64;

    // stage A = bf16(h[n0..n0+63])
#pragma unroll
    for (int j = 0; j < 4; j++) {
        int idx = tid + j * 256;
        int e = idx >> 4, ch = idx & 15;
        int node = n0 + e;
        if (node >= NN) node = NN - 1;
        const f32x4* p = (const f32x4*)&h[node * 128 + ch * 8];
        f32x4 a = p[0], b = p[1];
        s16x8 s;
#pragma unroll
        for (int t = 0; t < 4; t++) {
            s[t] = (short)f2bf(a[t]);
            s[t + 4] = (short)f2bf(b[t]);
        }
        *(s16x8*)&Alds[e * 136 + ch * 8] = s;
    }
    __syncthreads();

    const int lane = tid & 63;
    const int w = tid >> 6;
    const int ln15 = lane & 15;
    const int q8 = (lane >> 4) * 8, q4 = (lane >> 4) * 4;
    const int cbase = w * 64;  // this wave's 64 output cols (of 256)

    f32x4 acc[4][4];
#pragma unroll
    for (int et = 0; et < 4; et++)
#pragma unroll
        for (int nt = 0; nt < 4; nt++) acc[et][nt] = (f32x4){0.f, 0.f, 0.f, 0.f};
#pragma unroll
    for (int kk = 0; kk < 4; kk++) {
        int k0 = kk * 32 + q8;
        s16x8 a[4], b[4];
#pragma unroll
        for (int et = 0; et < 4; et++)
            a[et] = *(const s16x8*)&Alds[(et * 16 + ln15) * 136 + k0];
#pragma unroll
        for (int nt = 0; nt < 4; nt++)
            b[nt] = *(const s16x8*)&PWT[(cbase + nt * 16 + ln15) * 128 + k0];
#pragma unroll
        for (int et = 0; et < 4; et++)
#pragma unroll
            for (int nt = 0; nt < 4; nt++)
                acc[et][nt] = __builtin_amdgcn_mfma_f32_16x16x32_bf16(
                    a[et], b[nt], acc[et][nt], 0, 0, 0);
    }
#pragma unroll
    for (int nt = 0; nt < 4; nt++) {
        int cp = cbase + nt * 16 + ln15;
        unsigned short* dst = (cp < 128) ? P1 : P2;
        int col = cp & 127;
#pragma unroll
        for (int et = 0; et < 4; et++)
#pragma unroll
            for (int r = 0; r < 4; r++) {
                int row = et * 16 + q4 + r;
                int node = n0 + row;
                if (node >= NN) node = NN - 1;
                dst[node * 128 + col] = f2bf(acc[et][nt][r]);
            }
    }
}

// ---- edge kernel: 64 CSR-sorted edge slots per block ----
__global__ __launch_bounds__(256, 8) void edge_kernel(
    const unsigned short* __restrict__ P1, const unsigned short* __restrict__ P2,
    const float* __restrict__ x, const unsigned int* __restrict__ rc,
    const float* __restrict__ b1, const float* __restrict__ W1full,
    const unsigned short* __restrict__ W2T, const float* __restrict__ b2,
    const unsigned short* __restrict__ Wc1T, const float* __restrict__ bc1,
    const float* __restrict__ wc2,
    float* __restrict__ m_i, float* __restrict__ x_acc) {
    __shared__ unsigned short mid1[64 * 132];  // silu(e1) bf16; later m_ij (mid2)
    __shared__ float b1s[128], wls[128];
    __shared__ float rad[64], ndx[64], ndy[64], ndz[64], fsum[64];
    __shared__ int rowA[64], colA[64];

    const int tid = threadIdx.x;
    const int e0 = blockIdx.x * 64;

    if (tid < 64) {
        unsigned int pk = rc[e0 + tid];
        int r = pk & 0xffff, c = pk >> 16;
        rowA[tid] = r; colA[tid] = c;
        float dx = x[r * 3 + 0] - x[c * 3 + 0];
        float dy = x[r * 3 + 1] - x[c * 3 + 1];
        float dz = x[r * 3 + 2] - x[c * 3 + 2];
        float d2 = dx * dx + dy * dy + dz * dz;
        float dist = sqrtf(d2);
        float inv = 1.f / (dist + 1e-8f);
        rad[tid] = d2;
        ndx[tid] = dx * inv; ndy[tid] = dy * inv; ndz[tid] = dz * inv;
        fsum[tid] = 0.f;
    } else if (tid >= 128 && tid < 256) {
        int c = tid - 128;
        b1s[c] = b1[c];
        wls[c] = W1full[256 * 128 + c];
    }
    __syncthreads();

    // stage mid1 = silu(P1[row] + P2[col] + rad*wl + b1)  (e1 replaced by gather)
#pragma unroll
    for (int j = 0; j < 4; j++) {
        int idx = tid + j * 256;
        int e = idx >> 4, ch = idx & 15;
        int r = rowA[e], c = colA[e];
        s16x8 p1 = *(const s16x8*)&P1[(size_t)r * 128 + ch * 8];
        s16x8 p2 = *(const s16x8*)&P2[(size_t)c * 128 + ch * 8];
        float rd = rad[e];
        s16x8 s;
#pragma unroll
        for (int t = 0; t < 8; t++) {
            int col = ch * 8 + t;
            float v = bf2f((unsigned short)p1[t]) + bf2f((unsigned short)p2[t]) +
                      rd * wls[col] + b1s[col];
            s[t] = (short)f2bf(silu(v));
        }
        *(s16x8*)&mid1[e * 132 + ch * 8] = s;
    }
    __syncthreads();

    const int lane = tid & 63;
    const int w = tid >> 6;
    const int ln15 = lane & 15;
    const int q8 = (lane >> 4) * 8, q4 = (lane >> 4) * 4;
    const int nbase = w * 32;

    f32x4 acc[4][2];

    // ---- layer e2: silu([64x128]@W2 + b2) = m_ij
#pragma unroll
    for (int et = 0; et < 4; et++)
#pragma unroll
        for (int nt = 0; nt < 2; nt++) acc[et][nt] = (f32x4){0.f, 0.f, 0.f, 0.f};
#pragma unroll
    for (int kk = 0; kk < 4; kk++) {
        int k0 = kk * 32 + q8;
        s16x8 a[4], b[2];
#pragma unroll
        for (int et = 0; et < 4; et++)
            a[et] = *(const s16x8*)&mid1[(et * 16 + ln15) * 132 + k0];
#pragma unroll
        for (int nt = 0; nt < 2; nt++)
            b[nt] = *(const s16x8*)&W2T[(nbase + nt * 16 + ln15) * 128 + k0];
#pragma unroll
        for (int et = 0; et < 4; et++)
#pragma unroll
            for (int nt = 0; nt < 2; nt++)
                acc[et][nt] = __builtin_amdgcn_mfma_f32_16x16x32_bf16(
                    a[et], b[nt], acc[et][nt], 0, 0, 0);
    }
    __syncthreads();  // all mid1 reads done; reuse as mid2 (m_ij)
    unsigned short* mid2 = mid1;
#pragma unroll
    for (int nt = 0; nt < 2; nt++) {
        int col = nbase + nt * 16 + ln15;
        float bias = b2[col];
#pragma unroll
        for (int et = 0; et < 4; et++)
#pragma unroll
            for (int r = 0; r < 4; r++) {
                int row = et * 16 + q4 + r;
                mid2[row * 132 + col] = f2bf(silu(acc[et][nt][r] + bias));
            }
    }
    __syncthreads();

    // ---- coord layer: c1 = silu(m_ij @ Wc1 + bc1)
#pragma unroll
    for (int et = 0; et < 4; et++)
#pragma unroll
        for (int nt = 0; nt < 2; nt++) acc[et][nt] = (f32x4){0.f, 0.f, 0.f, 0.f};
#pragma unroll
    for (int kk = 0; kk < 4; kk++) {
        int k0 = kk * 32 + q8;
        s16x8 a[4], b[2];
#pragma unroll
        for (int et = 0; et < 4; et++)
            a[et] = *(const s16x8*)&mid2[(et * 16 + ln15) * 132 + k0];
#pragma unroll
        for (int nt = 0; nt < 2; nt++)
            b[nt] = *(const s16x8*)&Wc1T[(nbase + nt * 16 + ln15) * 128 + k0];
#pragma unroll
        for (int et = 0; et < 4; et++)
#pragma unroll
            for (int nt = 0; nt < 2; nt++)
                acc[et][nt] = __builtin_amdgcn_mfma_f32_16x16x32_bf16(
                    a[et], b[nt], acc[et][nt], 0, 0, 0);
    }

    // ---- m_i segment-reduce from mid2 (CSR-sorted rows -> few atomics) ----
    {
        int col = tid & 127;
        int r0 = (tid >> 7) * 32;  // rows [r0, r0+32)
        float accv = 0.f;
        int cur = rowA[r0];
        for (int row = r0; row < r0 + 32; row++) {
            int rn = rowA[row];
            if (rn != cur) {
                atomicAdd(&m_i[(size_t)cur * 128 + col], accv);
                accv = 0.f;
                cur = rn;
            }
            accv += bf2f(mid2[row * 132 + col]);
        }
        atomicAdd(&m_i[(size_t)cur * 128 + col], accv);
    }

    // ---- coord epilogue: fs = tanh(c1 . wc2) * 0.1
    {
        float part[4][4];
#pragma unroll
        for (int et = 0; et < 4; et++)
#pragma unroll
            for (int r = 0; r < 4; r++) part[et][r] = 0.f;
#pragma unroll
        for (int nt = 0; nt < 2; nt++) {
            int col = nbase + nt * 16 + ln15;
            float bias = bc1[col];
            float w2 = wc2[col];
#pragma unroll
            for (int et = 0; et < 4; et++)
#pragma unroll
                for (int r = 0; r < 4; r++)
                    part[et][r] += silu(acc[et][nt][r] + bias) * w2;
        }
#pragma unroll
        for (int et = 0; et < 4; et++)
#pragma unroll
            for (int r = 0; r < 4; r++) {
                float p = part[et][r];
                p += __shfl_xor(p, 8, 16);
                p += __shfl_xor(p, 4, 16);
                p += __shfl_xor(p, 2, 16);
                p += __shfl_xor(p, 1, 16);
                if (ln15 == 0) atomicAdd(&fsum[et * 16 + q4 + r], p);
            }
    }
    __syncthreads();
    // per-edge force into LDS, then segment-reduce per distinct row
    if (tid < 64) {
        float fs = tanhf(fsum[tid]) * 0.1f;
        ndx[tid] *= fs; ndy[tid] *= fs; ndz[tid] *= fs;
    }
    __syncthreads();
    if (tid < 64) {
        bool head = (tid == 0) || (rowA[tid] != rowA[tid - 1]);
        if (head) {
            int rn = rowA[tid];
            float ax = 0.f, ay = 0.f, az = 0.f;
            for (int j = tid; j < 64 && rowA[j] == rn; j++) {
                ax += ndx[j]; ay += ndy[j]; az += ndz[j];
            }
            atomicAdd(&x_acc[rn * 3 + 0], ax);
            atomicAdd(&x_acc[rn * 3 + 1], ay);
            atomicAdd(&x_acc[rn * 3 + 2], az);
        }
    }
}

// ---- node kernel: 64 nodes per block (dense m_i f32) ----
__global__ __launch_bounds__(256, 4) void node_kernel(
    const float* __restrict__ h, const float* __restrict__ m_i,
    const unsigned short* __restrict__ Wn1T, const float* __restrict__ bn1,
    const unsigned short* __restrict__ Wn2T, const float* __restrict__ bn2,
    const float* __restrict__ ln_g, const float* __restrict__ ln_b,
    float* __restrict__ out_h) {
    __shared__ unsigned short Alds[64 * 264];
    unsigned short* mid1 = Alds;
    float* tile = (float*)Alds;

    const int tid = threadIdx.x;
    const int n0 = blockIdx.x * 64;

    // stage A = [bf16(h) | bf16(m_i)]
#pragma unroll
    for (int i = 0; i < 8; i++) {
        int idx = tid + i * 256;
        int hr = idx >> 4, ch = idx & 15;
        int e = hr >> 1, half = hr & 1;
        int node = n0 + e;
        if (node >= NN) node = NN - 1;
        const float* src = half ? &m_i[(size_t)node * 128 + ch * 8]
                                : &h[(size_t)node * 128 + ch * 8];
        const f32x4* sp = (const f32x4*)src;
        f32x4 f0 = sp[0], f1 = sp[1];
        s16x8 s;
#pragma unroll
        for (int j = 0; j < 4; j++) {
            s[j] = (short)f2bf(f0[j]);
            s[j + 4] = (short)f2bf(f1[j]);
        }
        *(s16x8*)&Alds[e * 264 + half * 128 + ch * 8] = s;
    }
    __syncthreads();

    const int lane = tid & 63;
    const int w = tid >> 6;
    const int ln15 = lane & 15;
    const int q8 = (lane >> 4) * 8, q4 = (lane >> 4) * 4;
    const int nbase = w * 32;

    f32x4 acc[4][2];

    // ---- layer n1: K=256
#pragma unroll
    for (int et = 0; et < 4; et++)
#pragma unroll
        for (int nt = 0; nt < 2; nt++) acc[et][nt] = (f32x4){0.f, 0.f, 0.f, 0.f};
#pragma unroll
    for (int kk = 0; kk < 8; kk++) {
        int k0 = kk * 32 + q8;
        s16x8 a[4], b[2];
#pragma unroll
        for (int et = 0; et < 4; et++)
            a[et] = *(const s16x8*)&Alds[(et * 16 + ln15) * 264 + k0];
#pragma unroll
        for (int nt = 0; nt < 2; nt++)
            b[nt] = *(const s16x8*)&Wn1T[(nbase + nt * 16 + ln15) * 256 + k0];
#pragma unroll
        for (int et = 0; et < 4; et++)
#pragma unroll
            for (int nt = 0; nt < 2; nt++)
                acc[et][nt] = __builtin_amdgcn_mfma_f32_16x16x32_bf16(
                    a[et], b[nt], acc[et][nt], 0, 0, 0);
    }
    __syncthreads();  // A dead; mid1 overwrites
#pragma unroll
    for (int nt = 0; nt < 2; nt++) {
        int col = nbase + nt * 16 + ln15;
        float bias = bn1[col];
#pragma unroll
        for (int et = 0; et < 4; et++)
#pragma unroll
            for (int r = 0; r < 4; r++) {
                int row = et * 16 + q4 + r;
                mid1[row * 132 + col] = f2bf(silu(acc[et][nt][r] + bias));
            }
    }
    __syncthreads();

    // ---- layer n2: K=128
#pragma unroll
    for (int et = 0; et < 4; et++)
#pragma unroll
        for (int nt = 0; nt < 2; nt++) acc[et][nt] = (f32x4){0.f, 0.f, 0.f, 0.f};
#pragma unroll
    for (int kk = 0; kk < 4; kk++) {
        int k0 = kk * 32 + q8;
        s16x8 a[4], b[2];
#pragma unroll
        for (int et = 0; et < 4; et++)
            a[et] = *(const s16x8*)&mid1[(et * 16 + ln15) * 132 + k0];
#pragma unroll
        for (int nt = 0; nt < 2; nt++)
            b[nt] = *(const s16x8*)&Wn2T[(nbase + nt * 16 + ln15) * 128 + k0];
#pragma unroll
        for (int et = 0; et < 4; et++)
#pragma unroll
            for (int nt = 0; nt < 2; nt++)
                acc[et][nt] = __builtin_amdgcn_mfma_f32_16x16x32_bf16(
                    a[et], b[nt], acc[et][nt], 0, 0, 0);
    }
    __syncthreads();  // mid1 dead; f32 tile overwrites
#pragma unroll
    for (int nt = 0; nt < 2; nt++) {
        int col = nbase + nt * 16 + ln15;
        float bias = bn2[col];
#pragma unroll
        for (int et = 0; et < 4; et++)
#pragma unroll
            for (int r = 0; r < 4; r++) {
                int row = et * 16 + q4 + r;
                int node = n0 + row;
                int nclamp = node >= NN ? NN - 1 : node;
                float v = acc[et][nt][r] + bias + h[(size_t)nclamp * 128 + col];
                tile[row * 132 + col] = v;
            }
    }
    __syncthreads();

    // ---- LayerNorm: 4 threads/row, interleaved cols
    {
        int row = tid >> 2;
        int q = tid & 3;
        float s = 0.f, s2 = 0.f;
#pragma unroll
        for (int c = 0; c < 32; c++) {
            float v = tile[row * 132 + q + c * 4];
            s += v; s2 += v * v;
        }
        s += __shfl_xor(s, 1, 4);  s2 += __shfl_xor(s2, 1, 4);
        s += __shfl_xor(s, 2, 4);  s2 += __shfl_xor(s2, 2, 4);
        float mean = s * (1.f / 128.f);
        float var = s2 * (1.f / 128.f) - mean * mean;
        float rs = rsqrtf(var + 1e-5f);
        int node = n0 + row;
        if (node < NN) {
#pragma unroll
            for (int c = 0; c < 32; c++) {
                int col = q + c * 4;
                float v = (tile[row * 132 + col] - mean) * rs * ln_g[col] + ln_b[col];
                out_h[(size_t)node * 128 + col] = v;
            }
        }
    }
}

// ---- x update ----
__global__ void x_kernel(const float* __restrict__ x,
                         const float* __restrict__ x_acc,
                         float* __restrict__ out_x) {
    int i = blockIdx.x * 256 + threadIdx.x;
    if (i < NN * 3) out_x[i] = x[i] + x_acc[i];
}

extern "C" void kernel_launch(void* const* d_in, const int* in_sizes, int n_in,
                              void* d_out, int out_size, void* d_ws, size_t ws_size,
                              hipStream_t stream) {
    const float* h    = (const float*)d_in[0];
    const float* x    = (const float*)d_in[1];
    const int* eidx   = (const int*)d_in[2];
    const float* W_e1 = (const float*)d_in[3];
    const float* b_e1 = (const float*)d_in[4];
    const float* W_e2 = (const float*)d_in[5];
    const float* b_e2 = (const float*)d_in[6];
    const float* W_c1 = (const float*)d_in[7];
    const float* b_c1 = (const float*)d_in[8];
    const float* W_c2 = (const float*)d_in[9];
    const float* W_n1 = (const float*)d_in[10];
    const float* b_n1 = (const float*)d_in[11];
    const float* W_n2 = (const float*)d_in[12];
    const float* b_n2 = (const float*)d_in[13];
    const float* ln_g = (const float*)d_in[14];
    const float* ln_b = (const float*)d_in[15];

    float* out_h = (float*)d_out;
    float* out_x = out_h + NN * HH;

    char* ws = (char*)d_ws;
    // layout (total ~55.8 MB)
    float* m_i    = (float*)ws;                       // 25,600,000 (zero)
    float* x_acc  = (float*)(ws + 25600000);          //    600,000 (zero)
    int* counts   = (int*)(ws + 26200000);            //    200,000 (zero)
    int* cursor   = (int*)(ws + 26400000);            //    200,000 (zero)
    int* offsets  = (int*)(ws + 26600000);            //    200,000
    int* partials = (int*)(ws + 26800000);            //      1,024
    int* scanp    = (int*)(ws + 26801024);            //      1,024
    unsigned int* rc = (unsigned int*)(ws + 26802048);       //  3,200,000
    unsigned short* P1  = (unsigned short*)(ws + 30002048);  // 12,800,000
    unsigned short* P2  = (unsigned short*)(ws + 42802048);  // 12,800,000
    unsigned short* PWT = (unsigned short*)(ws + 55602048);  //     65,536
    unsigned short* W2T  = (unsigned short*)(ws + 55667584); //     32,768
    unsigned short* Wc1T = (unsigned short*)(ws + 55700352); //     32,768
    unsigned short* Wn1T = (unsigned short*)(ws + 55733120); //     65,536
    unsigned short* Wn2T = (unsigned short*)(ws + 55798656); //     32,768

    hipMemsetAsync(ws, 0, 26800000, stream);  // m_i + x_acc + counts + cursor
    transpose_pw<<<(256 * 128 + 255) / 256, 256, 0, stream>>>(W_e1, PWT);
    transpose_w<<<(128 * 128 + 255) / 256, 256, 0, stream>>>(W_e2, W2T, 128);
    transpose_w<<<(128 * 128 + 255) / 256, 256, 0, stream>>>(W_c1, Wc1T, 128);
    transpose_w<<<(128 * 256 + 255) / 256, 256, 0, stream>>>(W_n1, Wn1T, 256);
    transpose_w<<<(128 * 128 + 255) / 256, 256, 0, stream>>>(W_n2, Wn2T, 128);
    k_count<<<(NE + 255) / 256, 256, 0, stream>>>(eidx, counts);
    k_partial<<<SCAN_NB, 256, 0, stream>>>(counts, partials);
    k_scanp<<<1, 256, 0, stream>>>(partials, scanp);
    k_offsets<<<SCAN_NB, 256, 0, stream>>>(counts, scanp, offsets);
    k_fill<<<(NE + 255) / 256, 256, 0, stream>>>(eidx, offsets, cursor, rc);
    pgemm<<<(NN + 63) / 64, 256, 0, stream>>>(h, PWT, P1, P2);

    edge_kernel<<<NE / 64, 256, 0, stream>>>(P1, P2, x, rc, b_e1, W_e1, W2T,
                                             b_e2, Wc1T, b_c1, W_c2, m_i, x_acc);
    node_kernel<<<(NN + 63) / 64, 256, 0, stream>>>(h, m_i, Wn1T, b_n1, Wn2T,
                                                    b_n2, ln_g, ln_b, out_h);
    x_kernel<<<(NN * 3 + 255) / 256, 256, 0, stream>>>(x, x_acc, out_x);
}

// Round 7
// 453.129 us; speedup vs baseline: 1.5786x; 1.0817x over previous
//
#include <hip/hip_runtime.h>
#include <hip/hip_bf16.h>

#define NN 50000
#define NE 800000
#define HH 128
#define SCAN_NB 196  // ceil(50000/256)

typedef short s16x8 __attribute__((ext_vector_type(8)));
typedef float f32x4 __attribute__((ext_vector_type(4)));
typedef unsigned int u32x4 __attribute__((ext_vector_type(4)));
typedef __bf16 bf16x2 __attribute__((ext_vector_type(2)));

__device__ __forceinline__ float u2f(unsigned int v) {
    float f;
    __builtin_memcpy(&f, &v, 4);
    return f;
}
__device__ __forceinline__ float bf2f(unsigned short u) {
    return u2f(((unsigned int)u) << 16);
}
__device__ __forceinline__ unsigned short f2bf_sw(float f) {
    unsigned int x;
    __builtin_memcpy(&x, &f, 4);
    unsigned int r = (x + 0x7fffu + ((x >> 16) & 1u)) >> 16;
    return (unsigned short)r;
}
// packed f32x2 -> bf16x2 (HW RNE convert on gfx950)
__device__ __forceinline__ unsigned int f2bf_pk(float a, float b) {
#if __has_builtin(__builtin_amdgcn_cvt_pk_bf16_f32)
    bf16x2 p = __builtin_amdgcn_cvt_pk_bf16_f32(a, b);
    unsigned int u;
    __builtin_memcpy(&u, &p, 4);
    return u;
#else
    return (unsigned int)f2bf_sw(a) | ((unsigned int)f2bf_sw(b) << 16);
#endif
}
__device__ __forceinline__ unsigned short f2bf(float a) {
#if __has_builtin(__builtin_amdgcn_cvt_pk_bf16_f32)
    return (unsigned short)(f2bf_pk(a, a) & 0xffffu);
#else
    return f2bf_sw(a);
#endif
}
// fast silu: single v_rcp instead of IEEE divide
__device__ __forceinline__ float silu(float v) {
    return v * __builtin_amdgcn_rcpf(1.f + __expf(-v));
}

// ---- weight transpose+cast: W[k][128] f32 -> WT[n][K] bf16 ----
__global__ void transpose_w(const float* __restrict__ W,
                            unsigned short* __restrict__ WT, int K) {
    int idx = blockIdx.x * 256 + threadIdx.x;
    if (idx >= 128 * K) return;
    int n = idx / K, k = idx - n * K;
    WT[idx] = f2bf(W[k * 128 + n]);
}

// ---- PWT[c'][k]: c'<128 -> W_e1[k][c'] (W_top^T), else W_e1[128+k][c'-128] ----
__global__ void transpose_pw(const float* __restrict__ W1,
                             unsigned short* __restrict__ PWT) {
    int idx = blockIdx.x * 256 + threadIdx.x;
    if (idx >= 256 * 128) return;
    int cp = idx >> 7, k = idx & 127;
    int srow = (cp < 128) ? k : (128 + k);
    int scol = cp & 127;
    PWT[idx] = f2bf(W1[srow * 128 + scol]);
}

// ---- CSR build ----
__global__ void k_count(const int* __restrict__ eidx, int* __restrict__ counts) {
    int e = blockIdx.x * 256 + threadIdx.x;
    if (e >= NE) return;
    int r = eidx[e];
    r = r < 0 ? 0 : (r >= NN ? NN - 1 : r);
    atomicAdd(&counts[r], 1);
}
__global__ void k_partial(const int* __restrict__ counts, int* __restrict__ partials) {
    __shared__ int sm[256];
    int idx = blockIdx.x * 256 + threadIdx.x;
    sm[threadIdx.x] = idx < NN ? counts[idx] : 0;
    __syncthreads();
    for (int s = 128; s > 0; s >>= 1) {
        if (threadIdx.x < s) sm[threadIdx.x] += sm[threadIdx.x + s];
        __syncthreads();
    }
    if (threadIdx.x == 0) partials[blockIdx.x] = sm[0];
}
__global__ void k_scanp(const int* __restrict__ partials, int* __restrict__ scanp) {
    __shared__ int sm[256];
    int t = threadIdx.x;
    int v = t < SCAN_NB ? partials[t] : 0;
    sm[t] = v;
    __syncthreads();
    for (int d = 1; d < 256; d <<= 1) {
        int add = t >= d ? sm[t - d] : 0;
        __syncthreads();
        sm[t] += add;
        __syncthreads();
    }
    scanp[t] = sm[t] - v;  // exclusive
}
__global__ void k_offsets(const int* __restrict__ counts, const int* __restrict__ scanp,
                          int* __restrict__ offsets) {
    __shared__ int sm[256];
    int t = threadIdx.x, idx = blockIdx.x * 256 + t;
    int v = idx < NN ? counts[idx] : 0;
    sm[t] = v;
    __syncthreads();
    for (int d = 1; d < 256; d <<= 1) {
        int add = t >= d ? sm[t - d] : 0;
        __syncthreads();
        sm[t] += add;
        __syncthreads();
    }
    if (idx < NN) offsets[idx] = sm[t] - v + scanp[blockIdx.x];
}
// sort edges into CSR slot order; pack (r,c) as u16 pair (NN < 65536)
__global__ void k_fill(const int* __restrict__ eidx, const int* __restrict__ offsets,
                       int* __restrict__ cursor, unsigned int* __restrict__ rc) {
    int e = blockIdx.x * 256 + threadIdx.x;
    if (e >= NE) return;
    int r = eidx[e];
    int c = eidx[NE + e];
    r = r < 0 ? 0 : (r >= NN ? NN - 1 : r);
    c = c < 0 ? 0 : (c >= NN ? NN - 1 : c);
    int slot = offsets[r] + atomicAdd(&cursor[r], 1);
    rc[slot] = (unsigned int)r | ((unsigned int)c << 16);
}

// ---- P-GEMM: P1 = bf16(h) @ W_top, P2 = bf16(h) @ W_bot (bf16 out) ----
__global__ __launch_bounds__(256, 4) void pgemm(
    const float* __restrict__ h, const unsigned short* __restrict__ PWT,
    unsigned short* __restrict__ P1, unsigned short* __restrict__ P2) {
    __shared__ unsigned short Alds[64 * 136];
    const int tid = threadIdx.x;
    const int n0 = blockIdx.x * 64;

    // stage A = bf16(h[n0..n0+63])
#pragma unroll
    for (int j = 0; j < 4; j++) {
        int idx = tid + j * 256;
        int e = idx >> 4, ch = idx & 15;
        int node = n0 + e;
        if (node >= NN) node = NN - 1;
        const f32x4* p = (const f32x4*)&h[node * 128 + ch * 8];
        f32x4 a = p[0], b = p[1];
        u32x4 s;
        s[0] = f2bf_pk(a[0], a[1]);
        s[1] = f2bf_pk(a[2], a[3]);
        s[2] = f2bf_pk(b[0], b[1]);
        s[3] = f2bf_pk(b[2], b[3]);
        *(u32x4*)&Alds[e * 136 + ch * 8] = s;
    }
    __syncthreads();

    const int lane = tid & 63;
    const int w = tid >> 6;
    const int ln15 = lane & 15;
    const int q8 = (lane >> 4) * 8, q4 = (lane >> 4) * 4;
    const int cbase = w * 64;  // this wave's 64 output cols (of 256)

    f32x4 acc[4][4];
#pragma unroll
    for (int et = 0; et < 4; et++)
#pragma unroll
        for (int nt = 0; nt < 4; nt++) acc[et][nt] = (f32x4){0.f, 0.f, 0.f, 0.f};
#pragma unroll
    for (int kk = 0; kk < 4; kk++) {
        int k0 = kk * 32 + q8;
        s16x8 a[4], b[4];
#pragma unroll
        for (int et = 0; et < 4; et++)
            a[et] = *(const s16x8*)&Alds[(et * 16 + ln15) * 136 + k0];
#pragma unroll
        for (int nt = 0; nt < 4; nt++)
            b[nt] = *(const s16x8*)&PWT[(cbase + nt * 16 + ln15) * 128 + k0];
#pragma unroll
        for (int et = 0; et < 4; et++)
#pragma unroll
            for (int nt = 0; nt < 4; nt++)
                acc[et][nt] = __builtin_amdgcn_mfma_f32_16x16x32_bf16(
                    a[et], b[nt], acc[et][nt], 0, 0, 0);
    }
#pragma unroll
    for (int nt = 0; nt < 4; nt++) {
        int cp = cbase + nt * 16 + ln15;
        unsigned short* dst = (cp < 128) ? P1 : P2;
        int col = cp & 127;
#pragma unroll
        for (int et = 0; et < 4; et++)
#pragma unroll
            for (int r = 0; r < 4; r++) {
                int row = et * 16 + q4 + r;
                int node = n0 + row;
                if (node >= NN) node = NN - 1;
                dst[node * 128 + col] = f2bf(acc[et][nt][r]);
            }
    }
}

// ---- edge kernel: 64 CSR-sorted edge slots per block ----
__global__ __launch_bounds__(256, 8) void edge_kernel(
    const unsigned short* __restrict__ P1, const unsigned short* __restrict__ P2,
    const float* __restrict__ x, const unsigned int* __restrict__ rc,
    const float* __restrict__ b1, const float* __restrict__ W1full,
    const unsigned short* __restrict__ W2T, const float* __restrict__ b2,
    const unsigned short* __restrict__ Wc1T, const float* __restrict__ bc1,
    const float* __restrict__ wc2,
    float* __restrict__ m_i, float* __restrict__ x_acc) {
    __shared__ unsigned short mid1[64 * 132];  // silu(e1) bf16; later m_ij (mid2)
    __shared__ float b1s[128], wls[128];
    __shared__ float rad[64], ndx[64], ndy[64], ndz[64], fsum[64];
    __shared__ int rowA[64], colA[64];

    const int tid = threadIdx.x;
    const int e0 = blockIdx.x * 64;

    if (tid < 64) {
        unsigned int pk = rc[e0 + tid];
        int r = pk & 0xffff, c = pk >> 16;
        rowA[tid] = r; colA[tid] = c;
        float dx = x[r * 3 + 0] - x[c * 3 + 0];
        float dy = x[r * 3 + 1] - x[c * 3 + 1];
        float dz = x[r * 3 + 2] - x[c * 3 + 2];
        float d2 = dx * dx + dy * dy + dz * dz;
        float dist = sqrtf(d2);
        float inv = __builtin_amdgcn_rcpf(dist + 1e-8f);
        rad[tid] = d2;
        ndx[tid] = dx * inv; ndy[tid] = dy * inv; ndz[tid] = dz * inv;
        fsum[tid] = 0.f;
    } else if (tid >= 128 && tid < 256) {
        int c = tid - 128;
        b1s[c] = b1[c];
        wls[c] = W1full[256 * 128 + c];
    }
    __syncthreads();

    // stage mid1 = silu(P1[row] + P2[col] + rad*wl + b1)  (e1 replaced by gather)
#pragma unroll
    for (int j = 0; j < 4; j++) {
        int idx = tid + j * 256;
        int e = idx >> 4, ch = idx & 15;
        int r = rowA[e], c = colA[e];
        u32x4 p1 = *(const u32x4*)&P1[(size_t)r * 128 + ch * 8];
        u32x4 p2 = *(const u32x4*)&P2[(size_t)c * 128 + ch * 8];
        float rd = rad[e];
        u32x4 s;
#pragma unroll
        for (int t = 0; t < 4; t++) {
            int col = ch * 8 + t * 2;
            float a0 = u2f(p1[t] << 16), a1 = u2f(p1[t] & 0xffff0000u);
            float c0 = u2f(p2[t] << 16), c1 = u2f(p2[t] & 0xffff0000u);
            float v0 = a0 + c0 + rd * wls[col] + b1s[col];
            float v1 = a1 + c1 + rd * wls[col + 1] + b1s[col + 1];
            s[t] = f2bf_pk(silu(v0), silu(v1));
        }
        *(u32x4*)&mid1[e * 132 + ch * 8] = s;
    }
    __syncthreads();

    const int lane = tid & 63;
    const int w = tid >> 6;
    const int ln15 = lane & 15;
    const int q8 = (lane >> 4) * 8, q4 = (lane >> 4) * 4;
    const int nbase = w * 32;

    f32x4 acc[4][2];

    // ---- layer e2: silu([64x128]@W2 + b2) = m_ij
#pragma unroll
    for (int et = 0; et < 4; et++)
#pragma unroll
        for (int nt = 0; nt < 2; nt++) acc[et][nt] = (f32x4){0.f, 0.f, 0.f, 0.f};
#pragma unroll
    for (int kk = 0; kk < 4; kk++) {
        int k0 = kk * 32 + q8;
        s16x8 a[4], b[2];
#pragma unroll
        for (int et = 0; et < 4; et++)
            a[et] = *(const s16x8*)&mid1[(et * 16 + ln15) * 132 + k0];
#pragma unroll
        for (int nt = 0; nt < 2; nt++)
            b[nt] = *(const s16x8*)&W2T[(nbase + nt * 16 + ln15) * 128 + k0];
#pragma unroll
        for (int et = 0; et < 4; et++)
#pragma unroll
            for (int nt = 0; nt < 2; nt++)
                acc[et][nt] = __builtin_amdgcn_mfma_f32_16x16x32_bf16(
                    a[et], b[nt], acc[et][nt], 0, 0, 0);
    }
    __syncthreads();  // all mid1 reads done; reuse as mid2 (m_ij)
    unsigned short* mid2 = mid1;
#pragma unroll
    for (int nt = 0; nt < 2; nt++) {
        int col = nbase + nt * 16 + ln15;
        float bias = b2[col];
#pragma unroll
        for (int et = 0; et < 4; et++)
#pragma unroll
            for (int r = 0; r < 4; r++) {
                int row = et * 16 + q4 + r;
                mid2[row * 132 + col] = f2bf(silu(acc[et][nt][r] + bias));
            }
    }
    __syncthreads();

    // ---- coord layer: c1 = silu(m_ij @ Wc1 + bc1)
#pragma unroll
    for (int et = 0; et < 4; et++)
#pragma unroll
        for (int nt = 0; nt < 2; nt++) acc[et][nt] = (f32x4){0.f, 0.f, 0.f, 0.f};
#pragma unroll
    for (int kk = 0; kk < 4; kk++) {
        int k0 = kk * 32 + q8;
        s16x8 a[4], b[2];
#pragma unroll
        for (int et = 0; et < 4; et++)
            a[et] = *(const s16x8*)&mid2[(et * 16 + ln15) * 132 + k0];
#pragma unroll
        for (int nt = 0; nt < 2; nt++)
            b[nt] = *(const s16x8*)&Wc1T[(nbase + nt * 16 + ln15) * 128 + k0];
#pragma unroll
        for (int et = 0; et < 4; et++)
#pragma unroll
            for (int nt = 0; nt < 2; nt++)
                acc[et][nt] = __builtin_amdgcn_mfma_f32_16x16x32_bf16(
                    a[et], b[nt], acc[et][nt], 0, 0, 0);
    }

    // ---- m_i segment-reduce from mid2 (CSR-sorted rows -> few atomics) ----
    {
        int col = tid & 127;
        int r0 = (tid >> 7) * 32;  // rows [r0, r0+32)
        float accv = 0.f;
        int cur = rowA[r0];
        for (int row = r0; row < r0 + 32; row++) {
            int rn = rowA[row];
            if (rn != cur) {
                atomicAdd(&m_i[(size_t)cur * 128 + col], accv);
                accv = 0.f;
                cur = rn;
            }
            accv += bf2f(mid2[row * 132 + col]);
        }
        atomicAdd(&m_i[(size_t)cur * 128 + col], accv);
    }

    // ---- coord epilogue: fs = tanh(c1 . wc2) * 0.1
    {
        float part[4][4];
#pragma unroll
        for (int et = 0; et < 4; et++)
#pragma unroll
            for (int r = 0; r < 4; r++) part[et][r] = 0.f;
#pragma unroll
        for (int nt = 0; nt < 2; nt++) {
            int col = nbase + nt * 16 + ln15;
            float bias = bc1[col];
            float w2 = wc2[col];
#pragma unroll
            for (int et = 0; et < 4; et++)
#pragma unroll
                for (int r = 0; r < 4; r++)
                    part[et][r] += silu(acc[et][nt][r] + bias) * w2;
        }
#pragma unroll
        for (int et = 0; et < 4; et++)
#pragma unroll
            for (int r = 0; r < 4; r++) {
                float p = part[et][r];
                p += __shfl_xor(p, 8, 16);
                p += __shfl_xor(p, 4, 16);
                p += __shfl_xor(p, 2, 16);
                p += __shfl_xor(p, 1, 16);
                if (ln15 == 0) atomicAdd(&fsum[et * 16 + q4 + r], p);
            }
    }
    __syncthreads();
    // per-edge force into LDS, then segment-reduce per distinct row
    if (tid < 64) {
        float fs = tanhf(fsum[tid]) * 0.1f;
        ndx[tid] *= fs; ndy[tid] *= fs; ndz[tid] *= fs;
    }
    __syncthreads();
    if (tid < 64) {
        bool head = (tid == 0) || (rowA[tid] != rowA[tid - 1]);
        if (head) {
            int rn = rowA[tid];
            float ax = 0.f, ay = 0.f, az = 0.f;
            for (int j = tid; j < 64 && rowA[j] == rn; j++) {
                ax += ndx[j]; ay += ndy[j]; az += ndz[j];
            }
            atomicAdd(&x_acc[rn * 3 + 0], ax);
            atomicAdd(&x_acc[rn * 3 + 1], ay);
            atomicAdd(&x_acc[rn * 3 + 2], az);
        }
    }
}

// ---- node kernel: 64 nodes per block (dense m_i f32) ----
__global__ __launch_bounds__(256, 4) void node_kernel(
    const float* __restrict__ h, const float* __restrict__ m_i,
    const unsigned short* __restrict__ Wn1T, const float* __restrict__ bn1,
    const unsigned short* __restrict__ Wn2T, const float* __restrict__ bn2,
    const float* __restrict__ ln_g, const float* __restrict__ ln_b,
    float* __restrict__ out_h) {
    __shared__ unsigned short Alds[64 * 264];
    unsigned short* mid1 = Alds;
    float* tile = (float*)Alds;

    const int tid = threadIdx.x;
    const int n0 = blockIdx.x * 64;

    // stage A = [bf16(h) | bf16(m_i)]
#pragma unroll
    for (int i = 0; i < 8; i++) {
        int idx = tid + i * 256;
        int hr = idx >> 4, ch = idx & 15;
        int e = hr >> 1, half = hr & 1;
        int node = n0 + e;
        if (node >= NN) node = NN - 1;
        const float* src = half ? &m_i[(size_t)node * 128 + ch * 8]
                                : &h[(size_t)node * 128 + ch * 8];
        const f32x4* sp = (const f32x4*)src;
        f32x4 f0 = sp[0], f1 = sp[1];
        u32x4 s;
        s[0] = f2bf_pk(f0[0], f0[1]);
        s[1] = f2bf_pk(f0[2], f0[3]);
        s[2] = f2bf_pk(f1[0], f1[1]);
        s[3] = f2bf_pk(f1[2], f1[3]);
        *(u32x4*)&Alds[e * 264 + half * 128 + ch * 8] = s;
    }
    __syncthreads();

    const int lane = tid & 63;
    const int w = tid >> 6;
    const int ln15 = lane & 15;
    const int q8 = (lane >> 4) * 8, q4 = (lane >> 4) * 4;
    const int nbase = w * 32;

    f32x4 acc[4][2];

    // ---- layer n1: K=256
#pragma unroll
    for (int et = 0; et < 4; et++)
#pragma unroll
        for (int nt = 0; nt < 2; nt++) acc[et][nt] = (f32x4){0.f, 0.f, 0.f, 0.f};
#pragma unroll
    for (int kk = 0; kk < 8; kk++) {
        int k0 = kk * 32 + q8;
        s16x8 a[4], b[2];
#pragma unroll
        for (int et = 0; et < 4; et++)
            a[et] = *(const s16x8*)&Alds[(et * 16 + ln15) * 264 + k0];
#pragma unroll
        for (int nt = 0; nt < 2; nt++)
            b[nt] = *(const s16x8*)&Wn1T[(nbase + nt * 16 + ln15) * 256 + k0];
#pragma unroll
        for (int et = 0; et < 4; et++)
#pragma unroll
            for (int nt = 0; nt < 2; nt++)
                acc[et][nt] = __builtin_amdgcn_mfma_f32_16x16x32_bf16(
                    a[et], b[nt], acc[et][nt], 0, 0, 0);
    }
    __syncthreads();  // A dead; mid1 overwrites
#pragma unroll
    for (int nt = 0; nt < 2; nt++) {
        int col = nbase + nt * 16 + ln15;
        float bias = bn1[col];
#pragma unroll
        for (int et = 0; et < 4; et++)
#pragma unroll
            for (int r = 0; r < 4; r++) {
                int row = et * 16 + q4 + r;
                mid1[row * 132 + col] = f2bf(silu(acc[et][nt][r] + bias));
            }
    }
    __syncthreads();

    // ---- layer n2: K=128
#pragma unroll
    for (int et = 0; et < 4; et++)
#pragma unroll
        for (int nt = 0; nt < 2; nt++) acc[et][nt] = (f32x4){0.f, 0.f, 0.f, 0.f};
#pragma unroll
    for (int kk = 0; kk < 4; kk++) {
        int k0 = kk * 32 + q8;
        s16x8 a[4], b[2];
#pragma unroll
        for (int et = 0; et < 4; et++)
            a[et] = *(const s16x8*)&mid1[(et * 16 + ln15) * 132 + k0];
#pragma unroll
        for (int nt = 0; nt < 2; nt++)
            b[nt] = *(const s16x8*)&Wn2T[(nbase + nt * 16 + ln15) * 128 + k0];
#pragma unroll
        for (int et = 0; et < 4; et++)
#pragma unroll
            for (int nt = 0; nt < 2; nt++)
                acc[et][nt] = __builtin_amdgcn_mfma_f32_16x16x32_bf16(
                    a[et], b[nt], acc[et][nt], 0, 0, 0);
    }
    __syncthreads();  // mid1 dead; f32 tile overwrites
#pragma unroll
    for (int nt = 0; nt < 2; nt++) {
        int col = nbase + nt * 16 + ln15;
        float bias = bn2[col];
#pragma unroll
        for (int et = 0; et < 4; et++)
#pragma unroll
            for (int r = 0; r < 4; r++) {
                int row = et * 16 + q4 + r;
                int node = n0 + row;
                int nclamp = node >= NN ? NN - 1 : node;
                float v = acc[et][nt][r] + bias + h[(size_t)nclamp * 128 + col];
                tile[row * 132 + col] = v;
            }
    }
    __syncthreads();

    // ---- LayerNorm: 4 threads/row, interleaved cols
    {
        int row = tid >> 2;
        int q = tid & 3;
        float s = 0.f, s2 = 0.f;
#pragma unroll
        for (int c = 0; c < 32; c++) {
            float v = tile[row * 132 + q + c * 4];
            s += v; s2 += v * v;
        }
        s += __shfl_xor(s, 1, 4);  s2 += __shfl_xor(s2, 1, 4);
        s += __shfl_xor(s, 2, 4);  s2 += __shfl_xor(s2, 2, 4);
        float mean = s * (1.f / 128.f);
        float var = s2 * (1.f / 128.f) - mean * mean;
        float rs = rsqrtf(var + 1e-5f);
        int node = n0 + row;
        if (node < NN) {
#pragma unroll
            for (int c = 0; c < 32; c++) {
                int col = q + c * 4;
                float v = (tile[row * 132 + col] - mean) * rs * ln_g[col] + ln_b[col];
                out_h[(size_t)node * 128 + col] = v;
            }
        }
    }
}

// ---- x update ----
__global__ void x_kernel(const float* __restrict__ x,
                         const float* __restrict__ x_acc,
                         float* __restrict__ out_x) {
    int i = blockIdx.x * 256 + threadIdx.x;
    if (i < NN * 3) out_x[i] = x[i] + x_acc[i];
}

extern "C" void kernel_launch(void* const* d_in, const int* in_sizes, int n_in,
                              void* d_out, int out_size, void* d_ws, size_t ws_size,
                              hipStream_t stream) {
    const float* h    = (const float*)d_in[0];
    const float* x    = (const float*)d_in[1];
    const int* eidx   = (const int*)d_in[2];
    const float* W_e1 = (const float*)d_in[3];
    const float* b_e1 = (const float*)d_in[4];
    const float* W_e2 = (const float*)d_in[5];
    const float* b_e2 = (const float*)d_in[6];
    const float* W_c1 = (const float*)d_in[7];
    const float* b_c1 = (const float*)d_in[8];
    const float* W_c2 = (const float*)d_in[9];
    const float* W_n1 = (const float*)d_in[10];
    const float* b_n1 = (const float*)d_in[11];
    const float* W_n2 = (const float*)d_in[12];
    const float* b_n2 = (const float*)d_in[13];
    const float* ln_g = (const float*)d_in[14];
    const float* ln_b = (const float*)d_in[15];

    float* out_h = (float*)d_out;
    float* out_x = out_h + NN * HH;

    char* ws = (char*)d_ws;
    // layout (total ~55.8 MB)
    float* m_i    = (float*)ws;                       // 25,600,000 (zero)
    float* x_acc  = (float*)(ws + 25600000);          //    600,000 (zero)
    int* counts   = (int*)(ws + 26200000);            //    200,000 (zero)
    int* cursor   = (int*)(ws + 26400000);            //    200,000 (zero)
    int* offsets  = (int*)(ws + 26600000);            //    200,000
    int* partials = (int*)(ws + 26800000);            //      1,024
    int* scanp    = (int*)(ws + 26801024);            //      1,024
    unsigned int* rc = (unsigned int*)(ws + 26802048);       //  3,200,000
    unsigned short* P1  = (unsigned short*)(ws + 30002048);  // 12,800,000
    unsigned short* P2  = (unsigned short*)(ws + 42802048);  // 12,800,000
    unsigned short* PWT = (unsigned short*)(ws + 55602048);  //     65,536
    unsigned short* W2T  = (unsigned short*)(ws + 55667584); //     32,768
    unsigned short* Wc1T = (unsigned short*)(ws + 55700352); //     32,768
    unsigned short* Wn1T = (unsigned short*)(ws + 55733120); //     65,536
    unsigned short* Wn2T = (unsigned short*)(ws + 55798656); //     32,768

    hipMemsetAsync(ws, 0, 26800000, stream);  // m_i + x_acc + counts + cursor
    transpose_pw<<<(256 * 128 + 255) / 256, 256, 0, stream>>>(W_e1, PWT);
    transpose_w<<<(128 * 128 + 255) / 256, 256, 0, stream>>>(W_e2, W2T, 128);
    transpose_w<<<(128 * 128 + 255) / 256, 256, 0, stream>>>(W_c1, Wc1T, 128);
    transpose_w<<<(128 * 256 + 255) / 256, 256, 0, stream>>>(W_n1, Wn1T, 256);
    transpose_w<<<(128 * 128 + 255) / 256, 256, 0, stream>>>(W_n2, Wn2T, 128);
    k_count<<<(NE + 255) / 256, 256, 0, stream>>>(eidx, counts);
    k_partial<<<SCAN_NB, 256, 0, stream>>>(counts, partials);
    k_scanp<<<1, 256, 0, stream>>>(partials, scanp);
    k_offsets<<<SCAN_NB, 256, 0, stream>>>(counts, scanp, offsets);
    k_fill<<<(NE + 255) / 256, 256, 0, stream>>>(eidx, offsets, cursor, rc);
    pgemm<<<(NN + 63) / 64, 256, 0, stream>>>(h, PWT, P1, P2);

    edge_kernel<<<NE / 64, 256, 0, stream>>>(P1, P2, x, rc, b_e1, W_e1, W2T,
                                             b_e2, Wc1T, b_c1, W_c2, m_i, x_acc);
    node_kernel<<<(NN + 63) / 64, 256, 0, stream>>>(h, m_i, Wn1T, b_n1, Wn2T,
                                                    b_n2, ln_g, ln_b, out_h);
    x_kernel<<<(NN * 3 + 255) / 256, 256, 0, stream>>>(x, x_acc, out_x);
}